// Round 16
// baseline (221.678 us; speedup 1.0000x reference)
//
#include <hip/hip_runtime.h>
#include <hip/hip_bf16.h>

#define T_DIM 1024
#define B_DIM 32
#define D_DIM 256
#define TRACE 64
#define CTX 16
#define OUT_DIM 256
#define TB (T_DIM * B_DIM)          // 32768 rows
#define KZ (2 * TRACE * CTX)        // 2048
#define NP 640                      // concat proj width
#define NCH 16                      // scan chunks
#define CHL 64                      // chunk length

typedef short short8 __attribute__((ext_vector_type(8)));
typedef float floatx4 __attribute__((ext_vector_type(4)));
typedef unsigned short ushortx4 __attribute__((ext_vector_type(4)));

__device__ __forceinline__ float bf2f(unsigned short u) {
  return __uint_as_float((unsigned int)u << 16);
}
__device__ __forceinline__ float sigm(float v) {
  return 1.f / (1.f + expf(-v));
}
// async global->LDS, 16B per lane; LDS dest = wave-uniform base + lane*16
__device__ __forceinline__ void gload_lds16(const void* g, void* l) {
  __builtin_amdgcn_global_load_lds(
      (const __attribute__((address_space(1))) void*)g,
      (__attribute__((address_space(3))) void*)l, 16, 0, 0);
}

// ---------------------------------------------------------------------------
// K0: merged prep.
//  blocks [0,4096): xb = bf16(x)
//  blocks [4096,4128): start unpack (vectorized detect, 4 elems/thread)
//  blocks [4128,4256): wzt transpose
//  blocks [4256,4896): wcat/bcat
// ---------------------------------------------------------------------------
__global__ __launch_bounds__(256) void k_prep_all(
    const unsigned char* __restrict__ s, int* __restrict__ startw,
    const float* __restrict__ wz, __hip_bfloat16* __restrict__ wzt,
    const float* __restrict__ wgi, const float* __restrict__ bgi,
    const float* __restrict__ wpr, const float* __restrict__ bpr,
    const float* __restrict__ wgo, const float* __restrict__ bgo,
    const float* __restrict__ wsk, const float* __restrict__ bsk,
    __hip_bfloat16* __restrict__ wcat, float* __restrict__ bcat,
    const float* __restrict__ x, __hip_bfloat16* __restrict__ xb) {
  const int bid = blockIdx.x;
  const int tid = threadIdx.x;
  if (bid < 4096) {
    // ---- xb = bf16(x), 2048 elems/block ----
    size_t i = ((size_t)bid * 256 + tid) * 8;
    float4 a = *reinterpret_cast<const float4*>(x + i);
    float4 b = *reinterpret_cast<const float4*>(x + i + 4);
    unsigned short u[8];
    u[0] = __bfloat16_as_ushort(__float2bfloat16(a.x));
    u[1] = __bfloat16_as_ushort(__float2bfloat16(a.y));
    u[2] = __bfloat16_as_ushort(__float2bfloat16(a.z));
    u[3] = __bfloat16_as_ushort(__float2bfloat16(a.w));
    u[4] = __bfloat16_as_ushort(__float2bfloat16(b.x));
    u[5] = __bfloat16_as_ushort(__float2bfloat16(b.y));
    u[6] = __bfloat16_as_ushort(__float2bfloat16(b.z));
    u[7] = __bfloat16_as_ushort(__float2bfloat16(b.w));
    *reinterpret_cast<uint4*>(xb + i) = *reinterpret_cast<uint4*>(u);
    return;
  }
  if (bid < 4128) {
    // ---- start unpack; vectorized detection over first 32KB ----
    unsigned o1 = 0, o3 = 0, o4 = 0;
    for (int i = tid; i < 2048; i += 256) {
      uint4 wv = reinterpret_cast<const uint4*>(s)[i];
      unsigned allw = wv.x | wv.y | wv.z | wv.w;
      o1 |= allw & 0x0000FF00u;
      o3 |= allw & 0xFF000000u;
      o4 |= (wv.y | wv.w) & 0x000000FFu;
    }
    __shared__ unsigned s1, s3, s4;
    if (tid == 0) { s1 = 0; s3 = 0; s4 = 0; }
    __syncthreads();
    if (o1) atomicOr(&s1, 1u);
    if (o3) atomicOr(&s3, 1u);
    if (o4) atomicOr(&s4, 1u);
    __syncthreads();
    int f = s1 ? 1 : (s3 ? 2 : (s4 ? 0 : 3));
    int base = (bid - 4096) * 1024 + tid * 4;   // 4 elems/thread
    int4 v;
    if (f == 1) {
      uchar4 b4 = reinterpret_cast<const uchar4*>(s)[base >> 2];
      v = make_int4(b4.x != 0, b4.y != 0, b4.z != 0, b4.w != 0);
    } else if (f == 2) {
      float4 fv = reinterpret_cast<const float4*>(s)[base >> 2];
      v = make_int4(fv.x != 0.f, fv.y != 0.f, fv.z != 0.f, fv.w != 0.f);
    } else if (f == 3) {
      const long long* p = reinterpret_cast<const long long*>(s);
      v = make_int4(p[base] != 0, p[base + 1] != 0,
                    p[base + 2] != 0, p[base + 3] != 0);
    } else {
      int4 iv = reinterpret_cast<const int4*>(s)[base >> 2];
      v = make_int4(iv.x != 0, iv.y != 0, iv.z != 0, iv.w != 0);
    }
    reinterpret_cast<int4*>(startw)[base >> 2] = v;
    return;
  }
  if (bid < 4256) {
    // ---- wzt: wzt[n][k'] = bf16(w_z[perm(k')][n]), K-permute re/im adj ----
    const int t = bid - 4128;
    const int tk = t & 31;
    const int tn = t >> 5;
    const int k0 = tk * 64, n0 = tn * 64;
    __shared__ float sm[64][65];
    for (int i = tid; i < 4096; i += 256) {
      int r = i >> 6, c = i & 63;
      sm[r][c] = wz[(size_t)(k0 + r) * 256 + n0 + c];
    }
    __syncthreads();
    for (int i = tid; i < 4096; i += 256) {
      int r = i >> 6, c = i & 63;
      int src = (c & 0x20) | ((c & 1) << 4) | ((c >> 1) & 15);
      wzt[(size_t)(n0 + r) * 2048 + k0 + c] = __float2bfloat16(sm[src][r]);
    }
    return;
  }
  // ---- wcat/bcat ----
  const int n = bid - 4256, k = tid;
  float v, bv;
  if (n < 64)        { v = wgi[k * 64 + n];          bv = bgi[n]; }
  else if (n < 128)  { v = wpr[k * 64 + (n - 64)];   bv = bpr[n - 64]; }
  else if (n < 384)  { v = wgo[k * 256 + (n - 128)]; bv = bgo[n - 128]; }
  else               { v = wsk[k * 256 + (n - 384)]; bv = bsk[n - 384]; }
  wcat[(size_t)n * 256 + k] = __float2bfloat16(v);
  if (k == 0) bcat[n] = bv;
}

// ---------------------------------------------------------------------------
// Proj GEMM: proj = bf16( xb @ wcat^T + bcat ). M=32768, K=256, N=640.
// Both operands via global_load_lds (pre-swizzled source). Sigmoid in
// epilogue for gate planes. Bijective XCD swizzle (1280 = 8*160).
// ---------------------------------------------------------------------------
__global__ __launch_bounds__(256) void k_gemm_xproj(
    const __hip_bfloat16* __restrict__ A, const __hip_bfloat16* __restrict__ Bm,
    const float* __restrict__ bias, __hip_bfloat16* __restrict__ C) {
  int wg = (blockIdx.x & 7) * 160 + (blockIdx.x >> 3);
  const int n0 = (wg % 5) * 128;
  const int r0 = (wg / 5) * 128;
  const int tid = threadIdx.x;
  const int l = tid & 63;
  const int wid = tid >> 6;
  const int wr = wid >> 1;
  const int wc = wid & 1;

  __shared__ __align__(16) char ldsA[16384];
  __shared__ __align__(16) char ldsB[16384];

  floatx4 acc[4][4];
#pragma unroll
  for (int m = 0; m < 4; ++m)
#pragma unroll
    for (int n = 0; n < 4; ++n) acc[m][n] = (floatx4)0.f;

  int aoff[4][2], boff[4][2];
#pragma unroll
  for (int m = 0; m < 4; ++m) {
    int row = wr * 64 + m * 16 + (l & 15);
#pragma unroll
    for (int ks = 0; ks < 2; ++ks) {
      int byte = row * 128 + ks * 64 + (l >> 4) * 16;
      aoff[m][ks] = byte ^ ((row & 7) << 4);
    }
    int col = wc * 64 + m * 16 + (l & 15);
#pragma unroll
    for (int ks = 0; ks < 2; ++ks) {
      int byte = col * 128 + ks * 64 + (l >> 4) * 16;
      boff[m][ks] = byte ^ ((col & 7) << 4);
    }
  }

  for (int kt = 0; kt < 256; kt += 64) {
#pragma unroll
    for (int i = 0; i < 4; ++i) {
      int c = tid + i * 256;
      int row = c >> 3;
      int kgs = (c & 7) ^ (row & 7);
      gload_lds16(A + (size_t)(r0 + row) * 256 + kt + kgs * 8,
                  ldsA + i * 4096 + wid * 1024);
      gload_lds16(Bm + (size_t)(n0 + row) * 256 + kt + kgs * 8,
                  ldsB + i * 4096 + wid * 1024);
    }
    __syncthreads();
#pragma unroll
    for (int ks = 0; ks < 2; ++ks) {
      short8 a[4], b[4];
#pragma unroll
      for (int m = 0; m < 4; ++m)
        a[m] = *reinterpret_cast<const short8*>(ldsA + aoff[m][ks]);
#pragma unroll
      for (int n = 0; n < 4; ++n)
        b[n] = *reinterpret_cast<const short8*>(ldsB + boff[n][ks]);
#pragma unroll
      for (int m = 0; m < 4; ++m)
#pragma unroll
        for (int n = 0; n < 4; ++n)
          acc[m][n] = __builtin_amdgcn_mfma_f32_16x16x32_bf16(
              a[m], b[n], acc[m][n], 0, 0, 0);
    }
    __syncthreads();
  }

#pragma unroll
  for (int m = 0; m < 4; ++m) {
#pragma unroll
    for (int n = 0; n < 4; ++n) {
      int gc = n0 + wc * 64 + n * 16 + (l & 15);
      float bzv = bias[gc];
      bool dosig = (gc < 64) || (gc >= 128 && gc < 384);
#pragma unroll
      for (int j = 0; j < 4; ++j) {
        int gr = r0 + wr * 64 + m * 16 + (l >> 4) * 4 + j;
        float v = acc[m][n][j] + bzv;
        if (dosig) v = sigm(v);
        C[(size_t)gr * NP + gc] = __float2bfloat16(v);
      }
    }
  }
}

// ---------------------------------------------------------------------------
// Fused z-GEMM + LayerNorm, v6: A via gload_lds dbuf (16KB LDS only);
// B-frags read DIRECTLY from L2 into registers (wzt is 1MB, L2-resident).
// Halves LDS-pipe traffic (the v5 bottleneck); 3 blocks/CU.
// ---------------------------------------------------------------------------
__global__ __launch_bounds__(256, 3) void k_zgemm_ln(
    const __hip_bfloat16* __restrict__ zin, const __hip_bfloat16* __restrict__ wzt,
    const float* __restrict__ bz, const __hip_bfloat16* __restrict__ proj,
    float* __restrict__ out) {
  const int r0 = blockIdx.x * 64;
  const int tid = threadIdx.x;
  const int l = tid & 63;
  const int w = tid >> 6;            // wave id = N-slice

  __shared__ __align__(16) char lds[16384];   // A0 [0,8K) A1 [8K,16K)
  __shared__ float red1[256], red2[256];      // [row][wave]

  floatx4 acc[4][4];
#pragma unroll
  for (int m = 0; m < 4; ++m)
#pragma unroll
    for (int n = 0; n < 4; ++n) acc[m][n] = (floatx4)0.f;

  int aoff[4][2];
#pragma unroll
  for (int m = 0; m < 4; ++m) {
    int row = m * 16 + (l & 15);
#pragma unroll
    for (int ks = 0; ks < 2; ++ks) {
      int byte = row * 128 + ks * 64 + (l >> 4) * 16;
      aoff[m][ks] = byte ^ ((row & 7) << 4);
    }
  }
  // per-lane B base: col = w*64 + n*16 + (l&15), k-group = (l>>4)*8
  const __hip_bfloat16* bbase =
      wzt + (size_t)(w * 64 + (l & 15)) * KZ + (l >> 4) * 8;

  auto STAGE = [&](int kt, int sel) {
    char* pA = lds + (sel ? 8192 : 0);
#pragma unroll
    for (int i = 0; i < 2; ++i) {
      int c = tid + i * 256;
      int row = c >> 3;
      int kgs = (c & 7) ^ (row & 7);
      gload_lds16(zin + (size_t)(r0 + row) * KZ + kt + kgs * 8,
                  pA + i * 4096 + w * 1024);
    }
  };
  auto COMPUTE = [&](int sel, int kt) {
    const char* pA = lds + (sel ? 8192 : 0);
#pragma unroll
    for (int ks = 0; ks < 2; ++ks) {
      short8 a[4], b[4];
#pragma unroll
      for (int m = 0; m < 4; ++m)
        a[m] = *reinterpret_cast<const short8*>(pA + aoff[m][ks]);
#pragma unroll
      for (int n = 0; n < 4; ++n)
        b[n] = *reinterpret_cast<const short8*>(bbase + n * 16 * KZ + kt + ks * 32);
#pragma unroll
      for (int m = 0; m < 4; ++m)
#pragma unroll
        for (int n = 0; n < 4; ++n)
          acc[m][n] = __builtin_amdgcn_mfma_f32_16x16x32_bf16(
              a[m], b[n], acc[m][n], 0, 0, 0);
    }
  };

  STAGE(0, 0);
  asm volatile("s_waitcnt vmcnt(0)" ::: "memory");
  __builtin_amdgcn_s_barrier();
  for (int t = 0; t < 31; ++t) {
    STAGE((t + 1) * 64, (t + 1) & 1);
    COMPUTE(t & 1, t * 64);
    asm volatile("s_waitcnt vmcnt(0)" ::: "memory");
    __builtin_amdgcn_s_barrier();
  }
  COMPUTE(1, 31 * 64);

  float bzv[4];
#pragma unroll
  for (int n = 0; n < 4; ++n) bzv[n] = bz[w * 64 + n * 16 + (l & 15)];

  // phase 1: y in-place into acc, q = ps*(1-go), wave-local partial sums
  float q[4][4][4];
#pragma unroll
  for (int m = 0; m < 4; ++m) {
#pragma unroll
    for (int j = 0; j < 4; ++j) {
      int row = m * 16 + (l >> 4) * 4 + j;
      const __hip_bfloat16* prow = proj + (size_t)(r0 + row) * NP;
      float s1 = 0.f, s2 = 0.f;
#pragma unroll
      for (int n = 0; n < 4; ++n) {
        int col = w * 64 + n * 16 + (l & 15);
        float go = __bfloat162float(prow[128 + col]);   // sigm precomputed
        float ps = __bfloat162float(prow[384 + col]);
        float y = (acc[m][n][j] + bzv[n]) * go;
        acc[m][n][j] = y;
        q[m][n][j] = ps * (1.f - go);
        s1 += y;
        s2 += y * y;
      }
#pragma unroll
      for (int off = 8; off > 0; off >>= 1) {
        s1 += __shfl_xor(s1, off);
        s2 += __shfl_xor(s2, off);
      }
      if ((l & 15) == 0) { red1[row * 4 + w] = s1; red2[row * 4 + w] = s2; }
    }
  }
  __syncthreads();

  // phase 2: combine cross-wave sums, normalize, write out
#pragma unroll
  for (int m = 0; m < 4; ++m) {
#pragma unroll
    for (int j = 0; j < 4; ++j) {
      int row = m * 16 + (l >> 4) * 4 + j;
      int gr = r0 + row;
      float t1 = red1[row * 4 + 0] + red1[row * 4 + 1] +
                 red1[row * 4 + 2] + red1[row * 4 + 3];
      float t2 = red2[row * 4 + 0] + red2[row * 4 + 1] +
                 red2[row * 4 + 2] + red2[row * 4 + 3];
      float mu = t1 * (1.f / 256.f);
      float var = t2 * (1.f / 256.f) - mu * mu;
      float rs = rsqrtf(var + 1e-6f);
#pragma unroll
      for (int n = 0; n < 4; ++n) {
        int col = w * 64 + n * 16 + (l & 15);
        out[(size_t)gr * 256 + col] = (acc[m][n][j] - mu) * rs + q[m][n][j];
      }
    }
  }
}

// ---------------------------------------------------------------------------
// K2a: per-chunk local scan -> carry per chain; rst_any per (chunk,b).
// NCH=16 chunks of CHL=64. block = (chunk<15, b, tg); 64 thr = (tl, cx).
// ---------------------------------------------------------------------------
__global__ __launch_bounds__(64) void k_scan_a(
    const __hip_bfloat16* __restrict__ proj, const int* __restrict__ startw,
    const float* __restrict__ ffm_a, const float* __restrict__ ffm_b,
    float2* __restrict__ carry, int* __restrict__ rstflag) {
  const int c  = blockIdx.x >> 9;        // 0..14
  const int bb = (blockIdx.x >> 4) & 31;
  const int tg = blockIdx.x & 15;
  const int tid = threadIdx.x;
  const int tl = tid >> 4, cx = tid & 15;
  const int trace = tg * 4 + tl;
  const int t0 = c * CHL;
  __shared__ float gs[CHL * 4];
  __shared__ int ss[CHL];
  for (int t = tid; t < CHL; t += 64) {
    size_t base = ((size_t)(t0 + t) * B_DIM + bb) * NP + tg * 4;
    ushortx4 pg4 = *reinterpret_cast<const ushortx4*>(proj + base);
    ushortx4 pp4 = *reinterpret_cast<const ushortx4*>(proj + base + 64);
    float4 o;
    o.x = bf2f(pp4[0]) * bf2f(pg4[0]);
    o.y = bf2f(pp4[1]) * bf2f(pg4[1]);
    o.z = bf2f(pp4[2]) * bf2f(pg4[2]);
    o.w = bf2f(pp4[3]) * bf2f(pg4[3]);
    *reinterpret_cast<float4*>(&gs[t * 4]) = o;
    ss[t] = startw[(t0 + t) * B_DIM + bb];
  }
  __syncthreads();

  int any = __any(ss[tid] != 0);
  if (tid == 0 && tg == 0) rstflag[c * B_DIM + bb] = any;

  float decay = expf(-fabsf(ffm_a[trace]));
  float th = ffm_b[cx];
  float cr = decay * cosf(th);
  float ci = decay * sinf(th);
  float sr = 0.f, si = 0.f;
  for (int t = 0; t < CHL; ++t) {
    float g = gs[t * 4 + tl];
    int rst = ss[t];
    float nr = fmaf(sr, cr, fmaf(-si, ci, g));
    float ni = fmaf(sr, ci, si * cr);
    sr = rst ? g : nr;
    si = rst ? 0.f : ni;
  }
  carry[((size_t)(c * B_DIM + bb) * TRACE + trace) * CTX + cx] =
      make_float2(sr, si);
}

// ---------------------------------------------------------------------------
// K2c: combine carries -> chunk-start state, scan chunk writing zin.
// chunk 15 writes fstate (real part).
// ---------------------------------------------------------------------------
__global__ __launch_bounds__(64) void k_scan_c(
    const __hip_bfloat16* __restrict__ proj, const int* __restrict__ startw,
    const float* __restrict__ state_re, const float* __restrict__ state_im,
    const float* __restrict__ ffm_a, const float* __restrict__ ffm_b,
    const float2* __restrict__ carry, const int* __restrict__ rstflag,
    __hip_bfloat16* __restrict__ zin, float* __restrict__ fstate) {
  const int c  = blockIdx.x >> 9;        // 0..15
  const int bb = (blockIdx.x >> 4) & 31;
  const int tg = blockIdx.x & 15;
  const int tid = threadIdx.x;
  const int tl = tid >> 4, cx = tid & 15;
  const int trace = tg * 4 + tl;
  const int t0 = c * CHL;
  __shared__ float gs[CHL * 4];
  __shared__ int ss[CHL];
  for (int t = tid; t < CHL; t += 64) {
    size_t base = ((size_t)(t0 + t) * B_DIM + bb) * NP + tg * 4;
    ushortx4 pg4 = *reinterpret_cast<const ushortx4*>(proj + base);
    ushortx4 pp4 = *reinterpret_cast<const ushortx4*>(proj + base + 64);
    float4 o;
    o.x = bf2f(pp4[0]) * bf2f(pg4[0]);
    o.y = bf2f(pp4[1]) * bf2f(pg4[1]);
    o.z = bf2f(pp4[2]) * bf2f(pg4[2]);
    o.w = bf2f(pp4[3]) * bf2f(pg4[3]);
    *reinterpret_cast<float4*>(&gs[t * 4]) = o;
    ss[t] = startw[(t0 + t) * B_DIM + bb];
  }
  __syncthreads();

  float decay = expf(-fabsf(ffm_a[trace]));
  float th = ffm_b[cx];
  float cr = decay * cosf(th);
  float ci = decay * sinf(th);

  // e^{ab*CHL} by 6 complex squarings (CHL=64)
  float pr = cr, pi = ci;
#pragma unroll
  for (int q = 0; q < 6; ++q) {
    float nr = pr * pr - pi * pi;
    float ni = 2.f * pr * pi;
    pr = nr; pi = ni;
  }

  const int chain = (bb * TRACE + trace) * CTX + cx;
  float sr = state_re[chain];
  float si = state_im[chain];
  for (int j = 0; j < c; ++j) {
    float2 cj = carry[((size_t)(j * B_DIM + bb) * TRACE + trace) * CTX + cx];
    if (rstflag[j * B_DIM + bb]) {
      sr = cj.x; si = cj.y;
    } else {
      float nsr = fmaf(pr, sr, fmaf(-pi, si, cj.x));
      float nsi = fmaf(pr, si, fmaf(pi, sr, cj.y));
      sr = nsr; si = nsi;
    }
  }

  const size_t zbase = (size_t)trace * 32 + cx * 2;
  for (int t = 0; t < CHL; ++t) {
    float g = gs[t * 4 + tl];
    int rst = ss[t];
    float nr = fmaf(sr, cr, fmaf(-si, ci, g));
    float ni = fmaf(sr, ci, si * cr);
    sr = rst ? g : nr;
    si = rst ? 0.f : ni;
    unsigned int u = (unsigned int)__bfloat16_as_ushort(__float2bfloat16(sr)) |
                     ((unsigned int)__bfloat16_as_ushort(__float2bfloat16(si)) << 16);
    *reinterpret_cast<unsigned int*>(
        zin + ((size_t)(t0 + t) * B_DIM + bb) * KZ + zbase) = u;
  }
  if (c == NCH - 1) fstate[chain] = sr;
}

extern "C" void kernel_launch(void* const* d_in, const int* in_sizes, int n_in,
                              void* d_out, int out_size, void* d_ws, size_t ws_size,
                              hipStream_t stream) {
  const float* x         = (const float*)d_in[0];
  const unsigned char* start_raw = (const unsigned char*)d_in[1];
  const float* state_re  = (const float*)d_in[2];
  const float* state_im  = (const float*)d_in[3];
  const float* w_gate_in = (const float*)d_in[4];
  const float* b_gate_in = (const float*)d_in[5];
  const float* w_pre     = (const float*)d_in[6];
  const float* b_pre     = (const float*)d_in[7];
  const float* w_z       = (const float*)d_in[8];
  const float* b_z       = (const float*)d_in[9];
  const float* w_gate_out= (const float*)d_in[10];
  const float* b_gate_out= (const float*)d_in[11];
  const float* w_skip    = (const float*)d_in[12];
  const float* b_skip    = (const float*)d_in[13];
  const float* ffm_a     = (const float*)d_in[14];
  const float* ffm_b     = (const float*)d_in[15];

  // workspace layout
  char* ws = (char*)d_ws;
  int* startw   = (int*)(ws + 4096);                          // [4KB, 132KB)
  int* rstflag  = (int*)(ws + (132 << 10));                   // [132KB, 134KB)
  float* bcat   = (float*)(ws + (160 << 10));                 // [160KB, 163KB)
  __hip_bfloat16* wcat =
      (__hip_bfloat16*)(ws + (256 << 10));                    // [256KB, 576KB)
  __hip_bfloat16* wzt =
      (__hip_bfloat16*)(ws + ((size_t)1 << 20));              // [1MB, 2MB)
  float2* carry = (float2*)(ws + ((size_t)2 << 20));          // [2MB, 6MB)
  __hip_bfloat16* proj =
      (__hip_bfloat16*)(ws + ((size_t)6 << 20));              // [6MB, 46MB)
  __hip_bfloat16* xb =
      (__hip_bfloat16*)(ws + ((size_t)46 << 20));             // [46MB, 62MB)
  __hip_bfloat16* zin =
      (__hip_bfloat16*)(ws + ((size_t)62 << 20));             // [62MB, 190MB)

  float* fstate = (float*)d_out;                    // real(final_state), 32768
  float* out    = (float*)d_out + B_DIM * TRACE * CTX;

  k_prep_all<<<4896, 256, 0, stream>>>(
      start_raw, startw, w_z, wzt,
      w_gate_in, b_gate_in, w_pre, b_pre,
      w_gate_out, b_gate_out, w_skip, b_skip,
      wcat, bcat, x, xb);
  k_gemm_xproj<<<1280, 256, 0, stream>>>(xb, wcat, bcat, proj);
  k_scan_a<<<(NCH - 1) * B_DIM * 16, 64, 0, stream>>>(
      proj, startw, ffm_a, ffm_b, carry, rstflag);
  k_scan_c<<<NCH * B_DIM * 16, 64, 0, stream>>>(
      proj, startw, state_re, state_im, ffm_a, ffm_b, carry, rstflag,
      zin, fstate);
  k_zgemm_ln<<<TB / 64, 256, 0, stream>>>(zin, wzt, b_z, proj, out);
}

// Round 18
// 163.193 us; speedup vs baseline: 1.3584x; 1.3584x over previous
//
#include <hip/hip_runtime.h>
#include <hip/hip_bf16.h>

#define T_DIM 1024
#define B_DIM 32
#define D_DIM 256
#define TRACE 64
#define CTX 16
#define OUT_DIM 256
#define TB (T_DIM * B_DIM)          // 32768 rows
#define KZ (2 * TRACE * CTX)        // 2048
#define NP 640                      // concat proj width
#define NCH 16                      // scan chunks
#define CHL 64                      // chunk length

typedef short short8 __attribute__((ext_vector_type(8)));
typedef float floatx4 __attribute__((ext_vector_type(4)));
typedef unsigned short ushortx4 __attribute__((ext_vector_type(4)));

__device__ __forceinline__ float bf2f(unsigned short u) {
  return __uint_as_float((unsigned int)u << 16);
}
__device__ __forceinline__ float sigm(float v) {
  return 1.f / (1.f + expf(-v));
}
// async global->LDS, 16B per lane; LDS dest = wave-uniform base + lane*16
__device__ __forceinline__ void gload_lds16(const void* g, void* l) {
  __builtin_amdgcn_global_load_lds(
      (const __attribute__((address_space(1))) void*)g,
      (__attribute__((address_space(3))) void*)l, 16, 0, 0);
}

// ---------------------------------------------------------------------------
// K0: merged prep.
//  blocks [0,4096): xb = bf16(x)
//  blocks [4096,4128): start unpack (vectorized detect, 4 elems/thread)
//  blocks [4128,4256): wzt transpose
//  blocks [4256,4896): wcat/bcat
// ---------------------------------------------------------------------------
__global__ __launch_bounds__(256) void k_prep_all(
    const unsigned char* __restrict__ s, int* __restrict__ startw,
    const float* __restrict__ wz, __hip_bfloat16* __restrict__ wzt,
    const float* __restrict__ wgi, const float* __restrict__ bgi,
    const float* __restrict__ wpr, const float* __restrict__ bpr,
    const float* __restrict__ wgo, const float* __restrict__ bgo,
    const float* __restrict__ wsk, const float* __restrict__ bsk,
    __hip_bfloat16* __restrict__ wcat, float* __restrict__ bcat,
    const float* __restrict__ x, __hip_bfloat16* __restrict__ xb) {
  const int bid = blockIdx.x;
  const int tid = threadIdx.x;
  if (bid < 4096) {
    size_t i = ((size_t)bid * 256 + tid) * 8;
    float4 a = *reinterpret_cast<const float4*>(x + i);
    float4 b = *reinterpret_cast<const float4*>(x + i + 4);
    unsigned short u[8];
    u[0] = __bfloat16_as_ushort(__float2bfloat16(a.x));
    u[1] = __bfloat16_as_ushort(__float2bfloat16(a.y));
    u[2] = __bfloat16_as_ushort(__float2bfloat16(a.z));
    u[3] = __bfloat16_as_ushort(__float2bfloat16(a.w));
    u[4] = __bfloat16_as_ushort(__float2bfloat16(b.x));
    u[5] = __bfloat16_as_ushort(__float2bfloat16(b.y));
    u[6] = __bfloat16_as_ushort(__float2bfloat16(b.z));
    u[7] = __bfloat16_as_ushort(__float2bfloat16(b.w));
    *reinterpret_cast<uint4*>(xb + i) = *reinterpret_cast<uint4*>(u);
    return;
  }
  if (bid < 4128) {
    unsigned o1 = 0, o3 = 0, o4 = 0;
    for (int i = tid; i < 2048; i += 256) {
      uint4 wv = reinterpret_cast<const uint4*>(s)[i];
      unsigned allw = wv.x | wv.y | wv.z | wv.w;
      o1 |= allw & 0x0000FF00u;
      o3 |= allw & 0xFF000000u;
      o4 |= (wv.y | wv.w) & 0x000000FFu;
    }
    __shared__ unsigned s1, s3, s4;
    if (tid == 0) { s1 = 0; s3 = 0; s4 = 0; }
    __syncthreads();
    if (o1) atomicOr(&s1, 1u);
    if (o3) atomicOr(&s3, 1u);
    if (o4) atomicOr(&s4, 1u);
    __syncthreads();
    int f = s1 ? 1 : (s3 ? 2 : (s4 ? 0 : 3));
    int base = (bid - 4096) * 1024 + tid * 4;
    int4 v;
    if (f == 1) {
      uchar4 b4 = reinterpret_cast<const uchar4*>(s)[base >> 2];
      v = make_int4(b4.x != 0, b4.y != 0, b4.z != 0, b4.w != 0);
    } else if (f == 2) {
      float4 fv = reinterpret_cast<const float4*>(s)[base >> 2];
      v = make_int4(fv.x != 0.f, fv.y != 0.f, fv.z != 0.f, fv.w != 0.f);
    } else if (f == 3) {
      const long long* p = reinterpret_cast<const long long*>(s);
      v = make_int4(p[base] != 0, p[base + 1] != 0,
                    p[base + 2] != 0, p[base + 3] != 0);
    } else {
      int4 iv = reinterpret_cast<const int4*>(s)[base >> 2];
      v = make_int4(iv.x != 0, iv.y != 0, iv.z != 0, iv.w != 0);
    }
    reinterpret_cast<int4*>(startw)[base >> 2] = v;
    return;
  }
  if (bid < 4256) {
    const int t = bid - 4128;
    const int tk = t & 31;
    const int tn = t >> 5;
    const int k0 = tk * 64, n0 = tn * 64;
    __shared__ float sm[64][65];
    for (int i = tid; i < 4096; i += 256) {
      int r = i >> 6, c = i & 63;
      sm[r][c] = wz[(size_t)(k0 + r) * 256 + n0 + c];
    }
    __syncthreads();
    for (int i = tid; i < 4096; i += 256) {
      int r = i >> 6, c = i & 63;
      int src = (c & 0x20) | ((c & 1) << 4) | ((c >> 1) & 15);
      wzt[(size_t)(n0 + r) * 2048 + k0 + c] = __float2bfloat16(sm[src][r]);
    }
    return;
  }
  const int n = bid - 4256, k = tid;
  float v, bv;
  if (n < 64)        { v = wgi[k * 64 + n];          bv = bgi[n]; }
  else if (n < 128)  { v = wpr[k * 64 + (n - 64)];   bv = bpr[n - 64]; }
  else if (n < 384)  { v = wgo[k * 256 + (n - 128)]; bv = bgo[n - 128]; }
  else               { v = wsk[k * 256 + (n - 384)]; bv = bsk[n - 384]; }
  wcat[(size_t)n * 256 + k] = __float2bfloat16(v);
  if (k == 0) bcat[n] = bv;
}

// ---------------------------------------------------------------------------
// Proj GEMM v2: proj = bf16( xb @ wcat^T + bcat ). M=32768, K=256, N=640.
// Single-stage: whole 128x256 A,B tiles in LDS (64+64 KB), ONE barrier,
// then 8x16 back-to-back MFMAs. Swizzle: unit = ks*4+(l>>4), XOR row&7.
// Grid 1280 = 256 M-tiles x 5 N-tiles; bijective XCD swizzle (8*160).
// ---------------------------------------------------------------------------
__global__ __launch_bounds__(256) void k_gemm_xproj(
    const __hip_bfloat16* __restrict__ A, const __hip_bfloat16* __restrict__ Bm,
    const float* __restrict__ bias, __hip_bfloat16* __restrict__ C) {
  int wg = (blockIdx.x & 7) * 160 + (blockIdx.x >> 3);   // 1280 = 8*160
  const int n0 = (wg % 5) * 128;
  const int r0 = (wg / 5) * 128;
  const int tid = threadIdx.x;
  const int l = tid & 63;
  const int wid = tid >> 6;
  const int wr = wid >> 1;
  const int wc = wid & 1;

  __shared__ __align__(16) char ldsA[65536];   // [128][256] bf16, swz content
  __shared__ __align__(16) char ldsB[65536];

  floatx4 acc[4][4];
#pragma unroll
  for (int m = 0; m < 4; ++m)
#pragma unroll
    for (int n = 0; n < 4; ++n) acc[m][n] = (floatx4)0.f;

  // stage: 128 rows x 32 chunks of 16B each, pre-swizzled source
#pragma unroll
  for (int i = 0; i < 16; ++i) {
    int c = tid + i * 256;          // [0,4096)
    int row = c >> 5;
    int kgs = (c & 31) ^ (row & 7);
    gload_lds16(A + (size_t)(r0 + row) * 256 + kgs * 8, ldsA + (size_t)c * 16);
    gload_lds16(Bm + (size_t)(n0 + row) * 256 + kgs * 8, ldsB + (size_t)c * 16);
  }
  asm volatile("s_waitcnt vmcnt(0)" ::: "memory");
  __builtin_amdgcn_s_barrier();

#pragma unroll
  for (int ks = 0; ks < 8; ++ks) {
    short8 a[4], b[4];
#pragma unroll
    for (int m = 0; m < 4; ++m) {
      int row = wr * 64 + m * 16 + (l & 15);
      int unit = ((ks << 2) | (l >> 4)) ^ (row & 7);
      a[m] = *reinterpret_cast<const short8*>(ldsA + row * 512 + unit * 16);
    }
#pragma unroll
    for (int n = 0; n < 4; ++n) {
      int col = wc * 64 + n * 16 + (l & 15);
      int unit = ((ks << 2) | (l >> 4)) ^ (col & 7);
      b[n] = *reinterpret_cast<const short8*>(ldsB + col * 512 + unit * 16);
    }
#pragma unroll
    for (int m = 0; m < 4; ++m)
#pragma unroll
      for (int n = 0; n < 4; ++n)
        acc[m][n] = __builtin_amdgcn_mfma_f32_16x16x32_bf16(
            a[m], b[n], acc[m][n], 0, 0, 0);
  }

#pragma unroll
  for (int m = 0; m < 4; ++m) {
#pragma unroll
    for (int n = 0; n < 4; ++n) {
      int gc = n0 + wc * 64 + n * 16 + (l & 15);
      float bzv = bias[gc];
      bool dosig = (gc < 64) || (gc >= 128 && gc < 384);
#pragma unroll
      for (int j = 0; j < 4; ++j) {
        int gr = r0 + wr * 64 + m * 16 + (l >> 4) * 4 + j;
        float v = acc[m][n][j] + bzv;
        if (dosig) v = sigm(v);
        C[(size_t)gr * NP + gc] = __float2bfloat16(v);
      }
    }
  }
}

// ---------------------------------------------------------------------------
// Fused z-GEMM + LayerNorm, v5 (proven 54us): dbuf 80KB, gload_lds both
// operands, 2 blocks/CU, un-pinned schedule.
// ---------------------------------------------------------------------------
__global__ __launch_bounds__(256, 2) void k_zgemm_ln(
    const __hip_bfloat16* __restrict__ zin, const __hip_bfloat16* __restrict__ wzt,
    const float* __restrict__ bz, const __hip_bfloat16* __restrict__ proj,
    float* __restrict__ out) {
  const int r0 = blockIdx.x * 64;
  const int tid = threadIdx.x;
  const int l = tid & 63;
  const int w = tid >> 6;            // wave id = N-slice

  // layout: A0 [0,8K) A1 [8K,16K) B0 [16K,48K) B1 [48K,80K)
  __shared__ __align__(16) char lds[81920];
  float* red1 = (float*)lds;                   // alias A0: 64*4 floats
  float* red2 = (float*)(lds + 1024);

  floatx4 acc[4][4];
#pragma unroll
  for (int m = 0; m < 4; ++m)
#pragma unroll
    for (int n = 0; n < 4; ++n) acc[m][n] = (floatx4)0.f;

  int aoff[4][2], boff[4][2];
#pragma unroll
  for (int m = 0; m < 4; ++m) {
    int row = m * 16 + (l & 15);
#pragma unroll
    for (int ks = 0; ks < 2; ++ks) {
      int byte = row * 128 + ks * 64 + (l >> 4) * 16;
      aoff[m][ks] = byte ^ ((row & 7) << 4);
    }
  }
#pragma unroll
  for (int n = 0; n < 4; ++n) {
    int col = w * 64 + n * 16 + (l & 15);
#pragma unroll
    for (int ks = 0; ks < 2; ++ks) {
      int byte = col * 128 + ks * 64 + (l >> 4) * 16;
      boff[n][ks] = byte ^ ((col & 7) << 4);
    }
  }

  auto STAGE = [&](int kt, int sel) {
    char* pA = lds + (sel ? 8192 : 0);
    char* pB = lds + 16384 + (sel ? 32768 : 0);
#pragma unroll
    for (int i = 0; i < 2; ++i) {
      int c = tid + i * 256;
      int row = c >> 3;
      int kgs = (c & 7) ^ (row & 7);
      gload_lds16(zin + (size_t)(r0 + row) * KZ + kt + kgs * 8,
                  pA + i * 4096 + w * 1024);
    }
#pragma unroll
    for (int i = 0; i < 8; ++i) {
      int c = tid + i * 256;
      int row = c >> 3;
      int kgs = (c & 7) ^ (row & 7);
      gload_lds16(wzt + (size_t)row * KZ + kt + kgs * 8,
                  pB + i * 4096 + w * 1024);
    }
  };
  auto COMPUTE = [&](int sel) {
    const char* pA = lds + (sel ? 8192 : 0);
    const char* pB = lds + 16384 + (sel ? 32768 : 0);
#pragma unroll
    for (int ks = 0; ks < 2; ++ks) {
      short8 a[4], b[4];
#pragma unroll
      for (int m = 0; m < 4; ++m)
        a[m] = *reinterpret_cast<const short8*>(pA + aoff[m][ks]);
#pragma unroll
      for (int n = 0; n < 4; ++n)
        b[n] = *reinterpret_cast<const short8*>(pB + boff[n][ks]);
#pragma unroll
      for (int m = 0; m < 4; ++m)
#pragma unroll
        for (int n = 0; n < 4; ++n)
          acc[m][n] = __builtin_amdgcn_mfma_f32_16x16x32_bf16(
              a[m], b[n], acc[m][n], 0, 0, 0);
    }
  };

  STAGE(0, 0);
  asm volatile("s_waitcnt vmcnt(0)" ::: "memory");
  __builtin_amdgcn_s_barrier();
  for (int t = 0; t < 31; ++t) {
    STAGE((t + 1) * 64, (t + 1) & 1);
    COMPUTE(t & 1);
    asm volatile("s_waitcnt vmcnt(0)" ::: "memory");
    __builtin_amdgcn_s_barrier();
  }
  COMPUTE(1);  // tile 31 from buf1 — A0 now dead, red aliases it

  float bzv[4];
#pragma unroll
  for (int n = 0; n < 4; ++n) bzv[n] = bz[w * 64 + n * 16 + (l & 15)];

  float q[4][4][4];
#pragma unroll
  for (int m = 0; m < 4; ++m) {
#pragma unroll
    for (int j = 0; j < 4; ++j) {
      int row = m * 16 + (l >> 4) * 4 + j;
      const __hip_bfloat16* prow = proj + (size_t)(r0 + row) * NP;
      float s1 = 0.f, s2 = 0.f;
#pragma unroll
      for (int n = 0; n < 4; ++n) {
        int col = w * 64 + n * 16 + (l & 15);
        float go = __bfloat162float(prow[128 + col]);   // sigm precomputed
        float ps = __bfloat162float(prow[384 + col]);
        float y = (acc[m][n][j] + bzv[n]) * go;
        acc[m][n][j] = y;
        q[m][n][j] = ps * (1.f - go);
        s1 += y;
        s2 += y * y;
      }
#pragma unroll
      for (int off = 8; off > 0; off >>= 1) {
        s1 += __shfl_xor(s1, off);
        s2 += __shfl_xor(s2, off);
      }
      if ((l & 15) == 0) { red1[row * 4 + w] = s1; red2[row * 4 + w] = s2; }
    }
  }
  __syncthreads();

#pragma unroll
  for (int m = 0; m < 4; ++m) {
#pragma unroll
    for (int j = 0; j < 4; ++j) {
      int row = m * 16 + (l >> 4) * 4 + j;
      int gr = r0 + row;
      float t1 = red1[row * 4 + 0] + red1[row * 4 + 1] +
                 red1[row * 4 + 2] + red1[row * 4 + 3];
      float t2 = red2[row * 4 + 0] + red2[row * 4 + 1] +
                 red2[row * 4 + 2] + red2[row * 4 + 3];
      float mu = t1 * (1.f / 256.f);
      float var = t2 * (1.f / 256.f) - mu * mu;
      float rs = rsqrtf(var + 1e-6f);
#pragma unroll
      for (int n = 0; n < 4; ++n) {
        int col = w * 64 + n * 16 + (l & 15);
        out[(size_t)gr * 256 + col] = (acc[m][n][j] - mu) * rs + q[m][n][j];
      }
    }
  }
}

// ---------------------------------------------------------------------------
// K2a: per-chunk local scan -> carry per chain; rst_any per (chunk,b).
// NCH=16 chunks of CHL=64. block = (chunk<15, b, tg); 64 thr = (tl, cx).
// ---------------------------------------------------------------------------
__global__ __launch_bounds__(64) void k_scan_a(
    const __hip_bfloat16* __restrict__ proj, const int* __restrict__ startw,
    const float* __restrict__ ffm_a, const float* __restrict__ ffm_b,
    float2* __restrict__ carry, int* __restrict__ rstflag) {
  const int c  = blockIdx.x >> 9;        // 0..14
  const int bb = (blockIdx.x >> 4) & 31;
  const int tg = blockIdx.x & 15;
  const int tid = threadIdx.x;
  const int tl = tid >> 4, cx = tid & 15;
  const int trace = tg * 4 + tl;
  const int t0 = c * CHL;
  __shared__ float gs[CHL * 4];
  __shared__ int ss[CHL];
  for (int t = tid; t < CHL; t += 64) {
    size_t base = ((size_t)(t0 + t) * B_DIM + bb) * NP + tg * 4;
    ushortx4 pg4 = *reinterpret_cast<const ushortx4*>(proj + base);
    ushortx4 pp4 = *reinterpret_cast<const ushortx4*>(proj + base + 64);
    float4 o;
    o.x = bf2f(pp4[0]) * bf2f(pg4[0]);
    o.y = bf2f(pp4[1]) * bf2f(pg4[1]);
    o.z = bf2f(pp4[2]) * bf2f(pg4[2]);
    o.w = bf2f(pp4[3]) * bf2f(pg4[3]);
    *reinterpret_cast<float4*>(&gs[t * 4]) = o;
    ss[t] = startw[(t0 + t) * B_DIM + bb];
  }
  __syncthreads();

  int any = __any(ss[tid] != 0);
  if (tid == 0 && tg == 0) rstflag[c * B_DIM + bb] = any;

  float decay = expf(-fabsf(ffm_a[trace]));
  float th = ffm_b[cx];
  float cr = decay * cosf(th);
  float ci = decay * sinf(th);
  float sr = 0.f, si = 0.f;
  for (int t = 0; t < CHL; ++t) {
    float g = gs[t * 4 + tl];
    int rst = ss[t];
    float nr = fmaf(sr, cr, fmaf(-si, ci, g));
    float ni = fmaf(sr, ci, si * cr);
    sr = rst ? g : nr;
    si = rst ? 0.f : ni;
  }
  carry[((size_t)(c * B_DIM + bb) * TRACE + trace) * CTX + cx] =
      make_float2(sr, si);
}

// ---------------------------------------------------------------------------
// K2c: combine carries -> chunk-start state, scan chunk writing zin.
// chunk 15 writes fstate (real part).
// ---------------------------------------------------------------------------
__global__ __launch_bounds__(64) void k_scan_c(
    const __hip_bfloat16* __restrict__ proj, const int* __restrict__ startw,
    const float* __restrict__ state_re, const float* __restrict__ state_im,
    const float* __restrict__ ffm_a, const float* __restrict__ ffm_b,
    const float2* __restrict__ carry, const int* __restrict__ rstflag,
    __hip_bfloat16* __restrict__ zin, float* __restrict__ fstate) {
  const int c  = blockIdx.x >> 9;        // 0..15
  const int bb = (blockIdx.x >> 4) & 31;
  const int tg = blockIdx.x & 15;
  const int tid = threadIdx.x;
  const int tl = tid >> 4, cx = tid & 15;
  const int trace = tg * 4 + tl;
  const int t0 = c * CHL;
  __shared__ float gs[CHL * 4];
  __shared__ int ss[CHL];
  for (int t = tid; t < CHL; t += 64) {
    size_t base = ((size_t)(t0 + t) * B_DIM + bb) * NP + tg * 4;
    ushortx4 pg4 = *reinterpret_cast<const ushortx4*>(proj + base);
    ushortx4 pp4 = *reinterpret_cast<const ushortx4*>(proj + base + 64);
    float4 o;
    o.x = bf2f(pp4[0]) * bf2f(pg4[0]);
    o.y = bf2f(pp4[1]) * bf2f(pg4[1]);
    o.z = bf2f(pp4[2]) * bf2f(pg4[2]);
    o.w = bf2f(pp4[3]) * bf2f(pg4[3]);
    *reinterpret_cast<float4*>(&gs[t * 4]) = o;
    ss[t] = startw[(t0 + t) * B_DIM + bb];
  }
  __syncthreads();

  float decay = expf(-fabsf(ffm_a[trace]));
  float th = ffm_b[cx];
  float cr = decay * cosf(th);
  float ci = decay * sinf(th);

  // e^{ab*CHL} by 6 complex squarings (CHL=64)
  float pr = cr, pi = ci;
#pragma unroll
  for (int q = 0; q < 6; ++q) {
    float nr = pr * pr - pi * pi;
    float ni = 2.f * pr * pi;
    pr = nr; pi = ni;
  }

  const int chain = (bb * TRACE + trace) * CTX + cx;
  float sr = state_re[chain];
  float si = state_im[chain];
  for (int j = 0; j < c; ++j) {
    float2 cj = carry[((size_t)(j * B_DIM + bb) * TRACE + trace) * CTX + cx];
    if (rstflag[j * B_DIM + bb]) {
      sr = cj.x; si = cj.y;
    } else {
      float nsr = fmaf(pr, sr, fmaf(-pi, si, cj.x));
      float nsi = fmaf(pr, si, fmaf(pi, sr, cj.y));
      sr = nsr; si = nsi;
    }
  }

  const size_t zbase = (size_t)trace * 32 + cx * 2;
  for (int t = 0; t < CHL; ++t) {
    float g = gs[t * 4 + tl];
    int rst = ss[t];
    float nr = fmaf(sr, cr, fmaf(-si, ci, g));
    float ni = fmaf(sr, ci, si * cr);
    sr = rst ? g : nr;
    si = rst ? 0.f : ni;
    unsigned int u = (unsigned int)__bfloat16_as_ushort(__float2bfloat16(sr)) |
                     ((unsigned int)__bfloat16_as_ushort(__float2bfloat16(si)) << 16);
    *reinterpret_cast<unsigned int*>(
        zin + ((size_t)(t0 + t) * B_DIM + bb) * KZ + zbase) = u;
  }
  if (c == NCH - 1) fstate[chain] = sr;
}

extern "C" void kernel_launch(void* const* d_in, const int* in_sizes, int n_in,
                              void* d_out, int out_size, void* d_ws, size_t ws_size,
                              hipStream_t stream) {
  const float* x         = (const float*)d_in[0];
  const unsigned char* start_raw = (const unsigned char*)d_in[1];
  const float* state_re  = (const float*)d_in[2];
  const float* state_im  = (const float*)d_in[3];
  const float* w_gate_in = (const float*)d_in[4];
  const float* b_gate_in = (const float*)d_in[5];
  const float* w_pre     = (const float*)d_in[6];
  const float* b_pre     = (const float*)d_in[7];
  const float* w_z       = (const float*)d_in[8];
  const float* b_z       = (const float*)d_in[9];
  const float* w_gate_out= (const float*)d_in[10];
  const float* b_gate_out= (const float*)d_in[11];
  const float* w_skip    = (const float*)d_in[12];
  const float* b_skip    = (const float*)d_in[13];
  const float* ffm_a     = (const float*)d_in[14];
  const float* ffm_b     = (const float*)d_in[15];

  // workspace layout
  char* ws = (char*)d_ws;
  int* startw   = (int*)(ws + 4096);                          // [4KB, 132KB)
  int* rstflag  = (int*)(ws + (132 << 10));                   // [132KB, 134KB)
  float* bcat   = (float*)(ws + (160 << 10));                 // [160KB, 163KB)
  __hip_bfloat16* wcat =
      (__hip_bfloat16*)(ws + (256 << 10));                    // [256KB, 576KB)
  __hip_bfloat16* wzt =
      (__hip_bfloat16*)(ws + ((size_t)1 << 20));              // [1MB, 2MB)
  float2* carry = (float2*)(ws + ((size_t)2 << 20));          // [2MB, 6MB)
  __hip_bfloat16* proj =
      (__hip_bfloat16*)(ws + ((size_t)6 << 20));              // [6MB, 46MB)
  __hip_bfloat16* xb =
      (__hip_bfloat16*)(ws + ((size_t)46 << 20));             // [46MB, 62MB)
  __hip_bfloat16* zin =
      (__hip_bfloat16*)(ws + ((size_t)62 << 20));             // [62MB, 190MB)

  float* fstate = (float*)d_out;                    // real(final_state), 32768
  float* out    = (float*)d_out + B_DIM * TRACE * CTX;

  k_prep_all<<<4896, 256, 0, stream>>>(
      start_raw, startw, w_z, wzt,
      w_gate_in, b_gate_in, w_pre, b_pre,
      w_gate_out, b_gate_out, w_skip, b_skip,
      wcat, bcat, x, xb);
  k_gemm_xproj<<<1280, 256, 0, stream>>>(xb, wcat, bcat, proj);
  k_scan_a<<<(NCH - 1) * B_DIM * 16, 64, 0, stream>>>(
      proj, startw, ffm_a, ffm_b, carry, rstflag);
  k_scan_c<<<NCH * B_DIM * 16, 64, 0, stream>>>(
      proj, startw, state_re, state_im, ffm_a, ffm_b, carry, rstflag,
      zin, fstate);
  k_zgemm_ln<<<TB / 64, 256, 0, stream>>>(zin, wzt, b_z, proj, out);
}

// Round 19
// 147.315 us; speedup vs baseline: 1.5048x; 1.1078x over previous
//
#include <hip/hip_runtime.h>
#include <hip/hip_bf16.h>

#define T_DIM 1024
#define B_DIM 32
#define D_DIM 256
#define TRACE 64
#define CTX 16
#define OUT_DIM 256
#define TB (T_DIM * B_DIM)          // 32768 rows
#define KZ (2 * TRACE * CTX)        // 2048
#define NP 640                      // concat proj width
#define NCH 16                      // scan chunks
#define CHL 64                      // chunk length

typedef short short8 __attribute__((ext_vector_type(8)));
typedef float floatx4 __attribute__((ext_vector_type(4)));
typedef unsigned short ushortx4 __attribute__((ext_vector_type(4)));

__device__ __forceinline__ float bf2f(unsigned short u) {
  return __uint_as_float((unsigned int)u << 16);
}
__device__ __forceinline__ float sigm(float v) {
  return 1.f / (1.f + expf(-v));
}
// async global->LDS, 16B per lane; LDS dest = wave-uniform base + lane*16
__device__ __forceinline__ void gload_lds16(const void* g, void* l) {
  __builtin_amdgcn_global_load_lds(
      (const __attribute__((address_space(1))) void*)g,
      (__attribute__((address_space(3))) void*)l, 16, 0, 0);
}

// ---------------------------------------------------------------------------
// K0: merged prep.
//  blocks [0,4096): xb = bf16(x)
//  blocks [4096,4128): start unpack (vectorized detect, 4 elems/thread)
//  blocks [4128,4256): wzt transpose
//  blocks [4256,4896): wcat/bcat
// ---------------------------------------------------------------------------
__global__ __launch_bounds__(256) void k_prep_all(
    const unsigned char* __restrict__ s, int* __restrict__ startw,
    const float* __restrict__ wz, __hip_bfloat16* __restrict__ wzt,
    const float* __restrict__ wgi, const float* __restrict__ bgi,
    const float* __restrict__ wpr, const float* __restrict__ bpr,
    const float* __restrict__ wgo, const float* __restrict__ bgo,
    const float* __restrict__ wsk, const float* __restrict__ bsk,
    __hip_bfloat16* __restrict__ wcat, float* __restrict__ bcat,
    const float* __restrict__ x, __hip_bfloat16* __restrict__ xb) {
  const int bid = blockIdx.x;
  const int tid = threadIdx.x;
  if (bid < 4096) {
    size_t i = ((size_t)bid * 256 + tid) * 8;
    float4 a = *reinterpret_cast<const float4*>(x + i);
    float4 b = *reinterpret_cast<const float4*>(x + i + 4);
    unsigned short u[8];
    u[0] = __bfloat16_as_ushort(__float2bfloat16(a.x));
    u[1] = __bfloat16_as_ushort(__float2bfloat16(a.y));
    u[2] = __bfloat16_as_ushort(__float2bfloat16(a.z));
    u[3] = __bfloat16_as_ushort(__float2bfloat16(a.w));
    u[4] = __bfloat16_as_ushort(__float2bfloat16(b.x));
    u[5] = __bfloat16_as_ushort(__float2bfloat16(b.y));
    u[6] = __bfloat16_as_ushort(__float2bfloat16(b.z));
    u[7] = __bfloat16_as_ushort(__float2bfloat16(b.w));
    *reinterpret_cast<uint4*>(xb + i) = *reinterpret_cast<uint4*>(u);
    return;
  }
  if (bid < 4128) {
    unsigned o1 = 0, o3 = 0, o4 = 0;
    for (int i = tid; i < 2048; i += 256) {
      uint4 wv = reinterpret_cast<const uint4*>(s)[i];
      unsigned allw = wv.x | wv.y | wv.z | wv.w;
      o1 |= allw & 0x0000FF00u;
      o3 |= allw & 0xFF000000u;
      o4 |= (wv.y | wv.w) & 0x000000FFu;
    }
    __shared__ unsigned s1, s3, s4;
    if (tid == 0) { s1 = 0; s3 = 0; s4 = 0; }
    __syncthreads();
    if (o1) atomicOr(&s1, 1u);
    if (o3) atomicOr(&s3, 1u);
    if (o4) atomicOr(&s4, 1u);
    __syncthreads();
    int f = s1 ? 1 : (s3 ? 2 : (s4 ? 0 : 3));
    int base = (bid - 4096) * 1024 + tid * 4;
    int4 v;
    if (f == 1) {
      uchar4 b4 = reinterpret_cast<const uchar4*>(s)[base >> 2];
      v = make_int4(b4.x != 0, b4.y != 0, b4.z != 0, b4.w != 0);
    } else if (f == 2) {
      float4 fv = reinterpret_cast<const float4*>(s)[base >> 2];
      v = make_int4(fv.x != 0.f, fv.y != 0.f, fv.z != 0.f, fv.w != 0.f);
    } else if (f == 3) {
      const long long* p = reinterpret_cast<const long long*>(s);
      v = make_int4(p[base] != 0, p[base + 1] != 0,
                    p[base + 2] != 0, p[base + 3] != 0);
    } else {
      int4 iv = reinterpret_cast<const int4*>(s)[base >> 2];
      v = make_int4(iv.x != 0, iv.y != 0, iv.z != 0, iv.w != 0);
    }
    reinterpret_cast<int4*>(startw)[base >> 2] = v;
    return;
  }
  if (bid < 4256) {
    const int t = bid - 4128;
    const int tk = t & 31;
    const int tn = t >> 5;
    const int k0 = tk * 64, n0 = tn * 64;
    __shared__ float sm[64][65];
    for (int i = tid; i < 4096; i += 256) {
      int r = i >> 6, c = i & 63;
      sm[r][c] = wz[(size_t)(k0 + r) * 256 + n0 + c];
    }
    __syncthreads();
    for (int i = tid; i < 4096; i += 256) {
      int r = i >> 6, c = i & 63;
      int src = (c & 0x20) | ((c & 1) << 4) | ((c >> 1) & 15);
      wzt[(size_t)(n0 + r) * 2048 + k0 + c] = __float2bfloat16(sm[src][r]);
    }
    return;
  }
  const int n = bid - 4256, k = tid;
  float v, bv;
  if (n < 64)        { v = wgi[k * 64 + n];          bv = bgi[n]; }
  else if (n < 128)  { v = wpr[k * 64 + (n - 64)];   bv = bpr[n - 64]; }
  else if (n < 384)  { v = wgo[k * 256 + (n - 128)]; bv = bgo[n - 128]; }
  else               { v = wsk[k * 256 + (n - 384)]; bv = bsk[n - 384]; }
  wcat[(size_t)n * 256 + k] = __float2bfloat16(v);
  if (k == 0) bcat[n] = bv;
}

// ---------------------------------------------------------------------------
// Proj GEMM (R15-proven multi-stage): proj = bf16( xb @ wcat^T + bcat ).
// M=32768, K=256, N=640. Both operands via gload_lds (pre-swizzled source).
// Sigmoid in epilogue for gate planes. Bijective XCD swizzle (1280 = 8*160).
// ---------------------------------------------------------------------------
__global__ __launch_bounds__(256) void k_gemm_xproj(
    const __hip_bfloat16* __restrict__ A, const __hip_bfloat16* __restrict__ Bm,
    const float* __restrict__ bias, __hip_bfloat16* __restrict__ C) {
  int wg = (blockIdx.x & 7) * 160 + (blockIdx.x >> 3);
  const int n0 = (wg % 5) * 128;
  const int r0 = (wg / 5) * 128;
  const int tid = threadIdx.x;
  const int l = tid & 63;
  const int wid = tid >> 6;
  const int wr = wid >> 1;
  const int wc = wid & 1;

  __shared__ __align__(16) char ldsA[16384];
  __shared__ __align__(16) char ldsB[16384];

  floatx4 acc[4][4];
#pragma unroll
  for (int m = 0; m < 4; ++m)
#pragma unroll
    for (int n = 0; n < 4; ++n) acc[m][n] = (floatx4)0.f;

  int aoff[4][2], boff[4][2];
#pragma unroll
  for (int m = 0; m < 4; ++m) {
    int row = wr * 64 + m * 16 + (l & 15);
#pragma unroll
    for (int ks = 0; ks < 2; ++ks) {
      int byte = row * 128 + ks * 64 + (l >> 4) * 16;
      aoff[m][ks] = byte ^ ((row & 7) << 4);
    }
    int col = wc * 64 + m * 16 + (l & 15);
#pragma unroll
    for (int ks = 0; ks < 2; ++ks) {
      int byte = col * 128 + ks * 64 + (l >> 4) * 16;
      boff[m][ks] = byte ^ ((col & 7) << 4);
    }
  }

  for (int kt = 0; kt < 256; kt += 64) {
#pragma unroll
    for (int i = 0; i < 4; ++i) {
      int c = tid + i * 256;
      int row = c >> 3;
      int kgs = (c & 7) ^ (row & 7);
      gload_lds16(A + (size_t)(r0 + row) * 256 + kt + kgs * 8,
                  ldsA + i * 4096 + wid * 1024);
      gload_lds16(Bm + (size_t)(n0 + row) * 256 + kt + kgs * 8,
                  ldsB + i * 4096 + wid * 1024);
    }
    __syncthreads();
#pragma unroll
    for (int ks = 0; ks < 2; ++ks) {
      short8 a[4], b[4];
#pragma unroll
      for (int m = 0; m < 4; ++m)
        a[m] = *reinterpret_cast<const short8*>(ldsA + aoff[m][ks]);
#pragma unroll
      for (int n = 0; n < 4; ++n)
        b[n] = *reinterpret_cast<const short8*>(ldsB + boff[n][ks]);
#pragma unroll
      for (int m = 0; m < 4; ++m)
#pragma unroll
        for (int n = 0; n < 4; ++n)
          acc[m][n] = __builtin_amdgcn_mfma_f32_16x16x32_bf16(
              a[m], b[n], acc[m][n], 0, 0, 0);
    }
    __syncthreads();
  }

#pragma unroll
  for (int m = 0; m < 4; ++m) {
#pragma unroll
    for (int n = 0; n < 4; ++n) {
      int gc = n0 + wc * 64 + n * 16 + (l & 15);
      float bzv = bias[gc];
      bool dosig = (gc < 64) || (gc >= 128 && gc < 384);
#pragma unroll
      for (int j = 0; j < 4; ++j) {
        int gr = r0 + wr * 64 + m * 16 + (l >> 4) * 4 + j;
        float v = acc[m][n][j] + bzv;
        if (dosig) v = sigm(v);
        C[(size_t)gr * NP + gc] = __float2bfloat16(v);
      }
    }
  }
}

// ---------------------------------------------------------------------------
// Fused z-GEMM + LayerNorm, v7: dbuf + COUNTED vmcnt(10) (T4).
// Per step: STAGE(t+1) -> vmcnt(10) (tile t's loads landed; t+1's fly) ->
// barrier -> COMPUTE(t) -> barrier (no wave reads buf before overwrite).
// ---------------------------------------------------------------------------
__global__ __launch_bounds__(256, 2) void k_zgemm_ln(
    const __hip_bfloat16* __restrict__ zin, const __hip_bfloat16* __restrict__ wzt,
    const float* __restrict__ bz, const __hip_bfloat16* __restrict__ proj,
    float* __restrict__ out) {
  const int r0 = blockIdx.x * 64;
  const int tid = threadIdx.x;
  const int l = tid & 63;
  const int w = tid >> 6;            // wave id = N-slice

  // layout: A0 [0,8K) A1 [8K,16K) B0 [16K,48K) B1 [48K,80K)
  __shared__ __align__(16) char lds[81920];
  float* red1 = (float*)lds;                   // alias A0: 64*4 floats
  float* red2 = (float*)(lds + 1024);

  floatx4 acc[4][4];
#pragma unroll
  for (int m = 0; m < 4; ++m)
#pragma unroll
    for (int n = 0; n < 4; ++n) acc[m][n] = (floatx4)0.f;

  int aoff[4][2], boff[4][2];
#pragma unroll
  for (int m = 0; m < 4; ++m) {
    int row = m * 16 + (l & 15);
#pragma unroll
    for (int ks = 0; ks < 2; ++ks) {
      int byte = row * 128 + ks * 64 + (l >> 4) * 16;
      aoff[m][ks] = byte ^ ((row & 7) << 4);
    }
  }
#pragma unroll
  for (int n = 0; n < 4; ++n) {
    int col = w * 64 + n * 16 + (l & 15);
#pragma unroll
    for (int ks = 0; ks < 2; ++ks) {
      int byte = col * 128 + ks * 64 + (l >> 4) * 16;
      boff[n][ks] = byte ^ ((col & 7) << 4);
    }
  }

  auto STAGE = [&](int kt, int sel) {
    char* pA = lds + (sel ? 8192 : 0);
    char* pB = lds + 16384 + (sel ? 32768 : 0);
#pragma unroll
    for (int i = 0; i < 2; ++i) {
      int c = tid + i * 256;
      int row = c >> 3;
      int kgs = (c & 7) ^ (row & 7);
      gload_lds16(zin + (size_t)(r0 + row) * KZ + kt + kgs * 8,
                  pA + i * 4096 + w * 1024);
    }
#pragma unroll
    for (int i = 0; i < 8; ++i) {
      int c = tid + i * 256;
      int row = c >> 3;
      int kgs = (c & 7) ^ (row & 7);
      gload_lds16(wzt + (size_t)row * KZ + kt + kgs * 8,
                  pB + i * 4096 + w * 1024);
    }
  };
  auto COMPUTE = [&](int sel) {
    const char* pA = lds + (sel ? 8192 : 0);
    const char* pB = lds + 16384 + (sel ? 32768 : 0);
#pragma unroll
    for (int ks = 0; ks < 2; ++ks) {
      short8 a[4], b[4];
#pragma unroll
      for (int m = 0; m < 4; ++m)
        a[m] = *reinterpret_cast<const short8*>(pA + aoff[m][ks]);
#pragma unroll
      for (int n = 0; n < 4; ++n)
        b[n] = *reinterpret_cast<const short8*>(pB + boff[n][ks]);
#pragma unroll
      for (int m = 0; m < 4; ++m)
#pragma unroll
        for (int n = 0; n < 4; ++n)
          acc[m][n] = __builtin_amdgcn_mfma_f32_16x16x32_bf16(
              a[m], b[n], acc[m][n], 0, 0, 0);
    }
  };

  STAGE(0, 0);
  for (int t = 0; t < 31; ++t) {
    STAGE((t + 1) * 64, (t + 1) & 1);
    // tile t's 10 loads are older than the 10 just issued -> vmcnt(10)
    asm volatile("s_waitcnt vmcnt(10)" ::: "memory");
    __builtin_amdgcn_s_barrier();
    COMPUTE(t & 1);
    __builtin_amdgcn_s_barrier();   // protect buf[t] from STAGE(t+2) overwrite
  }
  asm volatile("s_waitcnt vmcnt(0)" ::: "memory");
  __builtin_amdgcn_s_barrier();
  COMPUTE(1);  // tile 31 from buf1 — A0 now dead, red aliases it

  float bzv[4];
#pragma unroll
  for (int n = 0; n < 4; ++n) bzv[n] = bz[w * 64 + n * 16 + (l & 15)];

  float q[4][4][4];
#pragma unroll
  for (int m = 0; m < 4; ++m) {
#pragma unroll
    for (int j = 0; j < 4; ++j) {
      int row = m * 16 + (l >> 4) * 4 + j;
      const __hip_bfloat16* prow = proj + (size_t)(r0 + row) * NP;
      float s1 = 0.f, s2 = 0.f;
#pragma unroll
      for (int n = 0; n < 4; ++n) {
        int col = w * 64 + n * 16 + (l & 15);
        float go = __bfloat162float(prow[128 + col]);   // sigm precomputed
        float ps = __bfloat162float(prow[384 + col]);
        float y = (acc[m][n][j] + bzv[n]) * go;
        acc[m][n][j] = y;
        q[m][n][j] = ps * (1.f - go);
        s1 += y;
        s2 += y * y;
      }
#pragma unroll
      for (int off = 8; off > 0; off >>= 1) {
        s1 += __shfl_xor(s1, off);
        s2 += __shfl_xor(s2, off);
      }
      if ((l & 15) == 0) { red1[row * 4 + w] = s1; red2[row * 4 + w] = s2; }
    }
  }
  __syncthreads();

#pragma unroll
  for (int m = 0; m < 4; ++m) {
#pragma unroll
    for (int j = 0; j < 4; ++j) {
      int row = m * 16 + (l >> 4) * 4 + j;
      int gr = r0 + row;
      float t1 = red1[row * 4 + 0] + red1[row * 4 + 1] +
                 red1[row * 4 + 2] + red1[row * 4 + 3];
      float t2 = red2[row * 4 + 0] + red2[row * 4 + 1] +
                 red2[row * 4 + 2] + red2[row * 4 + 3];
      float mu = t1 * (1.f / 256.f);
      float var = t2 * (1.f / 256.f) - mu * mu;
      float rs = rsqrtf(var + 1e-6f);
#pragma unroll
      for (int n = 0; n < 4; ++n) {
        int col = w * 64 + n * 16 + (l & 15);
        out[(size_t)gr * 256 + col] = (acc[m][n][j] - mu) * rs + q[m][n][j];
      }
    }
  }
}

// ---------------------------------------------------------------------------
// K2a: per-chunk local scan -> carry per chain; rst_any per (chunk,b).
// NCH=16 chunks of CHL=64. block = (chunk<15, b, tg); 64 thr = (tl, cx).
// ---------------------------------------------------------------------------
__global__ __launch_bounds__(64) void k_scan_a(
    const __hip_bfloat16* __restrict__ proj, const int* __restrict__ startw,
    const float* __restrict__ ffm_a, const float* __restrict__ ffm_b,
    float2* __restrict__ carry, int* __restrict__ rstflag) {
  const int c  = blockIdx.x >> 9;        // 0..14
  const int bb = (blockIdx.x >> 4) & 31;
  const int tg = blockIdx.x & 15;
  const int tid = threadIdx.x;
  const int tl = tid >> 4, cx = tid & 15;
  const int trace = tg * 4 + tl;
  const int t0 = c * CHL;
  __shared__ float gs[CHL * 4];
  __shared__ int ss[CHL];
  for (int t = tid; t < CHL; t += 64) {
    size_t base = ((size_t)(t0 + t) * B_DIM + bb) * NP + tg * 4;
    ushortx4 pg4 = *reinterpret_cast<const ushortx4*>(proj + base);
    ushortx4 pp4 = *reinterpret_cast<const ushortx4*>(proj + base + 64);
    float4 o;
    o.x = bf2f(pp4[0]) * bf2f(pg4[0]);
    o.y = bf2f(pp4[1]) * bf2f(pg4[1]);
    o.z = bf2f(pp4[2]) * bf2f(pg4[2]);
    o.w = bf2f(pp4[3]) * bf2f(pg4[3]);
    *reinterpret_cast<float4*>(&gs[t * 4]) = o;
    ss[t] = startw[(t0 + t) * B_DIM + bb];
  }
  __syncthreads();

  int any = __any(ss[tid] != 0);
  if (tid == 0 && tg == 0) rstflag[c * B_DIM + bb] = any;

  float decay = expf(-fabsf(ffm_a[trace]));
  float th = ffm_b[cx];
  float cr = decay * cosf(th);
  float ci = decay * sinf(th);
  float sr = 0.f, si = 0.f;
  for (int t = 0; t < CHL; ++t) {
    float g = gs[t * 4 + tl];
    int rst = ss[t];
    float nr = fmaf(sr, cr, fmaf(-si, ci, g));
    float ni = fmaf(sr, ci, si * cr);
    sr = rst ? g : nr;
    si = rst ? 0.f : ni;
  }
  carry[((size_t)(c * B_DIM + bb) * TRACE + trace) * CTX + cx] =
      make_float2(sr, si);
}

// ---------------------------------------------------------------------------
// K2c: combine carries -> chunk-start state, scan chunk writing zin.
// chunk 15 writes fstate (real part).
// ---------------------------------------------------------------------------
__global__ __launch_bounds__(64) void k_scan_c(
    const __hip_bfloat16* __restrict__ proj, const int* __restrict__ startw,
    const float* __restrict__ state_re, const float* __restrict__ state_im,
    const float* __restrict__ ffm_a, const float* __restrict__ ffm_b,
    const float2* __restrict__ carry, const int* __restrict__ rstflag,
    __hip_bfloat16* __restrict__ zin, float* __restrict__ fstate) {
  const int c  = blockIdx.x >> 9;        // 0..15
  const int bb = (blockIdx.x >> 4) & 31;
  const int tg = blockIdx.x & 15;
  const int tid = threadIdx.x;
  const int tl = tid >> 4, cx = tid & 15;
  const int trace = tg * 4 + tl;
  const int t0 = c * CHL;
  __shared__ float gs[CHL * 4];
  __shared__ int ss[CHL];
  for (int t = tid; t < CHL; t += 64) {
    size_t base = ((size_t)(t0 + t) * B_DIM + bb) * NP + tg * 4;
    ushortx4 pg4 = *reinterpret_cast<const ushortx4*>(proj + base);
    ushortx4 pp4 = *reinterpret_cast<const ushortx4*>(proj + base + 64);
    float4 o;
    o.x = bf2f(pp4[0]) * bf2f(pg4[0]);
    o.y = bf2f(pp4[1]) * bf2f(pg4[1]);
    o.z = bf2f(pp4[2]) * bf2f(pg4[2]);
    o.w = bf2f(pp4[3]) * bf2f(pg4[3]);
    *reinterpret_cast<float4*>(&gs[t * 4]) = o;
    ss[t] = startw[(t0 + t) * B_DIM + bb];
  }
  __syncthreads();

  float decay = expf(-fabsf(ffm_a[trace]));
  float th = ffm_b[cx];
  float cr = decay * cosf(th);
  float ci = decay * sinf(th);

  // e^{ab*CHL} by 6 complex squarings (CHL=64)
  float pr = cr, pi = ci;
#pragma unroll
  for (int q = 0; q < 6; ++q) {
    float nr = pr * pr - pi * pi;
    float ni = 2.f * pr * pi;
    pr = nr; pi = ni;
  }

  const int chain = (bb * TRACE + trace) * CTX + cx;
  float sr = state_re[chain];
  float si = state_im[chain];
  for (int j = 0; j < c; ++j) {
    float2 cj = carry[((size_t)(j * B_DIM + bb) * TRACE + trace) * CTX + cx];
    if (rstflag[j * B_DIM + bb]) {
      sr = cj.x; si = cj.y;
    } else {
      float nsr = fmaf(pr, sr, fmaf(-pi, si, cj.x));
      float nsi = fmaf(pr, si, fmaf(pi, sr, cj.y));
      sr = nsr; si = nsi;
    }
  }

  const size_t zbase = (size_t)trace * 32 + cx * 2;
  for (int t = 0; t < CHL; ++t) {
    float g = gs[t * 4 + tl];
    int rst = ss[t];
    float nr = fmaf(sr, cr, fmaf(-si, ci, g));
    float ni = fmaf(sr, ci, si * cr);
    sr = rst ? g : nr;
    si = rst ? 0.f : ni;
    unsigned int u = (unsigned int)__bfloat16_as_ushort(__float2bfloat16(sr)) |
                     ((unsigned int)__bfloat16_as_ushort(__float2bfloat16(si)) << 16);
    *reinterpret_cast<unsigned int*>(
        zin + ((size_t)(t0 + t) * B_DIM + bb) * KZ + zbase) = u;
  }
  if (c == NCH - 1) fstate[chain] = sr;
}

extern "C" void kernel_launch(void* const* d_in, const int* in_sizes, int n_in,
                              void* d_out, int out_size, void* d_ws, size_t ws_size,
                              hipStream_t stream) {
  const float* x         = (const float*)d_in[0];
  const unsigned char* start_raw = (const unsigned char*)d_in[1];
  const float* state_re  = (const float*)d_in[2];
  const float* state_im  = (const float*)d_in[3];
  const float* w_gate_in = (const float*)d_in[4];
  const float* b_gate_in = (const float*)d_in[5];
  const float* w_pre     = (const float*)d_in[6];
  const float* b_pre     = (const float*)d_in[7];
  const float* w_z       = (const float*)d_in[8];
  const float* b_z       = (const float*)d_in[9];
  const float* w_gate_out= (const float*)d_in[10];
  const float* b_gate_out= (const float*)d_in[11];
  const float* w_skip    = (const float*)d_in[12];
  const float* b_skip    = (const float*)d_in[13];
  const float* ffm_a     = (const float*)d_in[14];
  const float* ffm_b     = (const float*)d_in[15];

  // workspace layout
  char* ws = (char*)d_ws;
  int* startw   = (int*)(ws + 4096);                          // [4KB, 132KB)
  int* rstflag  = (int*)(ws + (132 << 10));                   // [132KB, 134KB)
  float* bcat   = (float*)(ws + (160 << 10));                 // [160KB, 163KB)
  __hip_bfloat16* wcat =
      (__hip_bfloat16*)(ws + (256 << 10));                    // [256KB, 576KB)
  __hip_bfloat16* wzt =
      (__hip_bfloat16*)(ws + ((size_t)1 << 20));              // [1MB, 2MB)
  float2* carry = (float2*)(ws + ((size_t)2 << 20));          // [2MB, 6MB)
  __hip_bfloat16* proj =
      (__hip_bfloat16*)(ws + ((size_t)6 << 20));              // [6MB, 46MB)
  __hip_bfloat16* xb =
      (__hip_bfloat16*)(ws + ((size_t)46 << 20));             // [46MB, 62MB)
  __hip_bfloat16* zin =
      (__hip_bfloat16*)(ws + ((size_t)62 << 20));             // [62MB, 190MB)

  float* fstate = (float*)d_out;                    // real(final_state), 32768
  float* out    = (float*)d_out + B_DIM * TRACE * CTX;

  k_prep_all<<<4896, 256, 0, stream>>>(
      start_raw, startw, w_z, wzt,
      w_gate_in, b_gate_in, w_pre, b_pre,
      w_gate_out, b_gate_out, w_skip, b_skip,
      wcat, bcat, x, xb);
  k_gemm_xproj<<<1280, 256, 0, stream>>>(xb, wcat, bcat, proj);
  k_scan_a<<<(NCH - 1) * B_DIM * 16, 64, 0, stream>>>(
      proj, startw, ffm_a, ffm_b, carry, rstflag);
  k_scan_c<<<NCH * B_DIM * 16, 64, 0, stream>>>(
      proj, startw, state_re, state_im, ffm_a, ffm_b, carry, rstflag,
      zin, fstate);
  k_zgemm_ln<<<TB / 64, 256, 0, stream>>>(zin, wzt, b_z, proj, out);
}

// Round 20
// 145.694 us; speedup vs baseline: 1.5215x; 1.0111x over previous
//
#include <hip/hip_runtime.h>
#include <hip/hip_bf16.h>

#define T_DIM 1024
#define B_DIM 32
#define D_DIM 256
#define TRACE 64
#define CTX 16
#define OUT_DIM 256
#define TB (T_DIM * B_DIM)          // 32768 rows
#define KZ (2 * TRACE * CTX)        // 2048
#define NP 640                      // concat proj width
#define NCH 16                      // scan chunks
#define CHL 64                      // chunk length

typedef short short8 __attribute__((ext_vector_type(8)));
typedef float floatx4 __attribute__((ext_vector_type(4)));
typedef unsigned short ushortx4 __attribute__((ext_vector_type(4)));

__device__ __forceinline__ float bf2f(unsigned short u) {
  return __uint_as_float((unsigned int)u << 16);
}
__device__ __forceinline__ float sigm(float v) {
  return 1.f / (1.f + expf(-v));
}
// async global->LDS, 16B per lane; LDS dest = wave-uniform base + lane*16
__device__ __forceinline__ void gload_lds16(const void* g, void* l) {
  __builtin_amdgcn_global_load_lds(
      (const __attribute__((address_space(1))) void*)g,
      (__attribute__((address_space(3))) void*)l, 16, 0, 0);
}

// ---------------------------------------------------------------------------
// K0: merged prep.
//  blocks [0,4096): xb = bf16(x)
//  blocks [4096,4128): start unpack (vectorized detect, 4 elems/thread)
//  blocks [4128,4256): wzt transpose
//  blocks [4256,4896): wcat/bcat
// ---------------------------------------------------------------------------
__global__ __launch_bounds__(256) void k_prep_all(
    const unsigned char* __restrict__ s, int* __restrict__ startw,
    const float* __restrict__ wz, __hip_bfloat16* __restrict__ wzt,
    const float* __restrict__ wgi, const float* __restrict__ bgi,
    const float* __restrict__ wpr, const float* __restrict__ bpr,
    const float* __restrict__ wgo, const float* __restrict__ bgo,
    const float* __restrict__ wsk, const float* __restrict__ bsk,
    __hip_bfloat16* __restrict__ wcat, float* __restrict__ bcat,
    const float* __restrict__ x, __hip_bfloat16* __restrict__ xb) {
  const int bid = blockIdx.x;
  const int tid = threadIdx.x;
  if (bid < 4096) {
    size_t i = ((size_t)bid * 256 + tid) * 8;
    float4 a = *reinterpret_cast<const float4*>(x + i);
    float4 b = *reinterpret_cast<const float4*>(x + i + 4);
    unsigned short u[8];
    u[0] = __bfloat16_as_ushort(__float2bfloat16(a.x));
    u[1] = __bfloat16_as_ushort(__float2bfloat16(a.y));
    u[2] = __bfloat16_as_ushort(__float2bfloat16(a.z));
    u[3] = __bfloat16_as_ushort(__float2bfloat16(a.w));
    u[4] = __bfloat16_as_ushort(__float2bfloat16(b.x));
    u[5] = __bfloat16_as_ushort(__float2bfloat16(b.y));
    u[6] = __bfloat16_as_ushort(__float2bfloat16(b.z));
    u[7] = __bfloat16_as_ushort(__float2bfloat16(b.w));
    *reinterpret_cast<uint4*>(xb + i) = *reinterpret_cast<uint4*>(u);
    return;
  }
  if (bid < 4128) {
    unsigned o1 = 0, o3 = 0, o4 = 0;
    for (int i = tid; i < 2048; i += 256) {
      uint4 wv = reinterpret_cast<const uint4*>(s)[i];
      unsigned allw = wv.x | wv.y | wv.z | wv.w;
      o1 |= allw & 0x0000FF00u;
      o3 |= allw & 0xFF000000u;
      o4 |= (wv.y | wv.w) & 0x000000FFu;
    }
    __shared__ unsigned s1, s3, s4;
    if (tid == 0) { s1 = 0; s3 = 0; s4 = 0; }
    __syncthreads();
    if (o1) atomicOr(&s1, 1u);
    if (o3) atomicOr(&s3, 1u);
    if (o4) atomicOr(&s4, 1u);
    __syncthreads();
    int f = s1 ? 1 : (s3 ? 2 : (s4 ? 0 : 3));
    int base = (bid - 4096) * 1024 + tid * 4;
    int4 v;
    if (f == 1) {
      uchar4 b4 = reinterpret_cast<const uchar4*>(s)[base >> 2];
      v = make_int4(b4.x != 0, b4.y != 0, b4.z != 0, b4.w != 0);
    } else if (f == 2) {
      float4 fv = reinterpret_cast<const float4*>(s)[base >> 2];
      v = make_int4(fv.x != 0.f, fv.y != 0.f, fv.z != 0.f, fv.w != 0.f);
    } else if (f == 3) {
      const long long* p = reinterpret_cast<const long long*>(s);
      v = make_int4(p[base] != 0, p[base + 1] != 0,
                    p[base + 2] != 0, p[base + 3] != 0);
    } else {
      int4 iv = reinterpret_cast<const int4*>(s)[base >> 2];
      v = make_int4(iv.x != 0, iv.y != 0, iv.z != 0, iv.w != 0);
    }
    reinterpret_cast<int4*>(startw)[base >> 2] = v;
    return;
  }
  if (bid < 4256) {
    const int t = bid - 4128;
    const int tk = t & 31;
    const int tn = t >> 5;
    const int k0 = tk * 64, n0 = tn * 64;
    __shared__ float sm[64][65];
    for (int i = tid; i < 4096; i += 256) {
      int r = i >> 6, c = i & 63;
      sm[r][c] = wz[(size_t)(k0 + r) * 256 + n0 + c];
    }
    __syncthreads();
    for (int i = tid; i < 4096; i += 256) {
      int r = i >> 6, c = i & 63;
      int src = (c & 0x20) | ((c & 1) << 4) | ((c >> 1) & 15);
      wzt[(size_t)(n0 + r) * 2048 + k0 + c] = __float2bfloat16(sm[src][r]);
    }
    return;
  }
  const int n = bid - 4256, k = tid;
  float v, bv;
  if (n < 64)        { v = wgi[k * 64 + n];          bv = bgi[n]; }
  else if (n < 128)  { v = wpr[k * 64 + (n - 64)];   bv = bpr[n - 64]; }
  else if (n < 384)  { v = wgo[k * 256 + (n - 128)]; bv = bgo[n - 128]; }
  else               { v = wsk[k * 256 + (n - 384)]; bv = bsk[n - 384]; }
  wcat[(size_t)n * 256 + k] = __float2bfloat16(v);
  if (k == 0) bcat[n] = bv;
}

// ---------------------------------------------------------------------------
// Proj GEMM (R15-proven multi-stage): proj = bf16( xb @ wcat^T + bcat ).
// ---------------------------------------------------------------------------
__global__ __launch_bounds__(256) void k_gemm_xproj(
    const __hip_bfloat16* __restrict__ A, const __hip_bfloat16* __restrict__ Bm,
    const float* __restrict__ bias, __hip_bfloat16* __restrict__ C) {
  int wg = (blockIdx.x & 7) * 160 + (blockIdx.x >> 3);
  const int n0 = (wg % 5) * 128;
  const int r0 = (wg / 5) * 128;
  const int tid = threadIdx.x;
  const int l = tid & 63;
  const int wid = tid >> 6;
  const int wr = wid >> 1;
  const int wc = wid & 1;

  __shared__ __align__(16) char ldsA[16384];
  __shared__ __align__(16) char ldsB[16384];

  floatx4 acc[4][4];
#pragma unroll
  for (int m = 0; m < 4; ++m)
#pragma unroll
    for (int n = 0; n < 4; ++n) acc[m][n] = (floatx4)0.f;

  int aoff[4][2], boff[4][2];
#pragma unroll
  for (int m = 0; m < 4; ++m) {
    int row = wr * 64 + m * 16 + (l & 15);
#pragma unroll
    for (int ks = 0; ks < 2; ++ks) {
      int byte = row * 128 + ks * 64 + (l >> 4) * 16;
      aoff[m][ks] = byte ^ ((row & 7) << 4);
    }
    int col = wc * 64 + m * 16 + (l & 15);
#pragma unroll
    for (int ks = 0; ks < 2; ++ks) {
      int byte = col * 128 + ks * 64 + (l >> 4) * 16;
      boff[m][ks] = byte ^ ((col & 7) << 4);
    }
  }

  for (int kt = 0; kt < 256; kt += 64) {
#pragma unroll
    for (int i = 0; i < 4; ++i) {
      int c = tid + i * 256;
      int row = c >> 3;
      int kgs = (c & 7) ^ (row & 7);
      gload_lds16(A + (size_t)(r0 + row) * 256 + kt + kgs * 8,
                  ldsA + i * 4096 + wid * 1024);
      gload_lds16(Bm + (size_t)(n0 + row) * 256 + kt + kgs * 8,
                  ldsB + i * 4096 + wid * 1024);
    }
    __syncthreads();
#pragma unroll
    for (int ks = 0; ks < 2; ++ks) {
      short8 a[4], b[4];
#pragma unroll
      for (int m = 0; m < 4; ++m)
        a[m] = *reinterpret_cast<const short8*>(ldsA + aoff[m][ks]);
#pragma unroll
      for (int n = 0; n < 4; ++n)
        b[n] = *reinterpret_cast<const short8*>(ldsB + boff[n][ks]);
#pragma unroll
      for (int m = 0; m < 4; ++m)
#pragma unroll
        for (int n = 0; n < 4; ++n)
          acc[m][n] = __builtin_amdgcn_mfma_f32_16x16x32_bf16(
              a[m], b[n], acc[m][n], 0, 0, 0);
    }
    __syncthreads();
  }

#pragma unroll
  for (int m = 0; m < 4; ++m) {
#pragma unroll
    for (int n = 0; n < 4; ++n) {
      int gc = n0 + wc * 64 + n * 16 + (l & 15);
      float bzv = bias[gc];
      bool dosig = (gc < 64) || (gc >= 128 && gc < 384);
#pragma unroll
      for (int j = 0; j < 4; ++j) {
        int gr = r0 + wr * 64 + m * 16 + (l >> 4) * 4 + j;
        float v = acc[m][n][j] + bzv;
        if (dosig) v = sigm(v);
        C[(size_t)gr * NP + gc] = __float2bfloat16(v);
      }
    }
  }
}

// ---------------------------------------------------------------------------
// Fused z-GEMM + LayerNorm, v5 (R15-proven 54us): dbuf 80KB, one barrier
// per K-step, un-pinned schedule.
// ---------------------------------------------------------------------------
__global__ __launch_bounds__(256, 2) void k_zgemm_ln(
    const __hip_bfloat16* __restrict__ zin, const __hip_bfloat16* __restrict__ wzt,
    const float* __restrict__ bz, const __hip_bfloat16* __restrict__ proj,
    float* __restrict__ out) {
  const int r0 = blockIdx.x * 64;
  const int tid = threadIdx.x;
  const int l = tid & 63;
  const int w = tid >> 6;            // wave id = N-slice

  // layout: A0 [0,8K) A1 [8K,16K) B0 [16K,48K) B1 [48K,80K)
  __shared__ __align__(16) char lds[81920];
  float* red1 = (float*)lds;                   // alias A0: 64*4 floats
  float* red2 = (float*)(lds + 1024);

  floatx4 acc[4][4];
#pragma unroll
  for (int m = 0; m < 4; ++m)
#pragma unroll
    for (int n = 0; n < 4; ++n) acc[m][n] = (floatx4)0.f;

  int aoff[4][2], boff[4][2];
#pragma unroll
  for (int m = 0; m < 4; ++m) {
    int row = m * 16 + (l & 15);
#pragma unroll
    for (int ks = 0; ks < 2; ++ks) {
      int byte = row * 128 + ks * 64 + (l >> 4) * 16;
      aoff[m][ks] = byte ^ ((row & 7) << 4);
    }
  }
#pragma unroll
  for (int n = 0; n < 4; ++n) {
    int col = w * 64 + n * 16 + (l & 15);
#pragma unroll
    for (int ks = 0; ks < 2; ++ks) {
      int byte = col * 128 + ks * 64 + (l >> 4) * 16;
      boff[n][ks] = byte ^ ((col & 7) << 4);
    }
  }

  auto STAGE = [&](int kt, int sel) {
    char* pA = lds + (sel ? 8192 : 0);
    char* pB = lds + 16384 + (sel ? 32768 : 0);
#pragma unroll
    for (int i = 0; i < 2; ++i) {
      int c = tid + i * 256;
      int row = c >> 3;
      int kgs = (c & 7) ^ (row & 7);
      gload_lds16(zin + (size_t)(r0 + row) * KZ + kt + kgs * 8,
                  pA + i * 4096 + w * 1024);
    }
#pragma unroll
    for (int i = 0; i < 8; ++i) {
      int c = tid + i * 256;
      int row = c >> 3;
      int kgs = (c & 7) ^ (row & 7);
      gload_lds16(wzt + (size_t)row * KZ + kt + kgs * 8,
                  pB + i * 4096 + w * 1024);
    }
  };
  auto COMPUTE = [&](int sel) {
    const char* pA = lds + (sel ? 8192 : 0);
    const char* pB = lds + 16384 + (sel ? 32768 : 0);
#pragma unroll
    for (int ks = 0; ks < 2; ++ks) {
      short8 a[4], b[4];
#pragma unroll
      for (int m = 0; m < 4; ++m)
        a[m] = *reinterpret_cast<const short8*>(pA + aoff[m][ks]);
#pragma unroll
      for (int n = 0; n < 4; ++n)
        b[n] = *reinterpret_cast<const short8*>(pB + boff[n][ks]);
#pragma unroll
      for (int m = 0; m < 4; ++m)
#pragma unroll
        for (int n = 0; n < 4; ++n)
          acc[m][n] = __builtin_amdgcn_mfma_f32_16x16x32_bf16(
              a[m], b[n], acc[m][n], 0, 0, 0);
    }
  };

  STAGE(0, 0);
  asm volatile("s_waitcnt vmcnt(0)" ::: "memory");
  __builtin_amdgcn_s_barrier();
  for (int t = 0; t < 31; ++t) {
    STAGE((t + 1) * 64, (t + 1) & 1);
    COMPUTE(t & 1);
    asm volatile("s_waitcnt vmcnt(0)" ::: "memory");
    __builtin_amdgcn_s_barrier();
  }
  COMPUTE(1);  // tile 31 from buf1 — A0 now dead, red aliases it

  float bzv[4];
#pragma unroll
  for (int n = 0; n < 4; ++n) bzv[n] = bz[w * 64 + n * 16 + (l & 15)];

  float q[4][4][4];
#pragma unroll
  for (int m = 0; m < 4; ++m) {
#pragma unroll
    for (int j = 0; j < 4; ++j) {
      int row = m * 16 + (l >> 4) * 4 + j;
      const __hip_bfloat16* prow = proj + (size_t)(r0 + row) * NP;
      float s1 = 0.f, s2 = 0.f;
#pragma unroll
      for (int n = 0; n < 4; ++n) {
        int col = w * 64 + n * 16 + (l & 15);
        float go = __bfloat162float(prow[128 + col]);   // sigm precomputed
        float ps = __bfloat162float(prow[384 + col]);
        float y = (acc[m][n][j] + bzv[n]) * go;
        acc[m][n][j] = y;
        q[m][n][j] = ps * (1.f - go);
        s1 += y;
        s2 += y * y;
      }
#pragma unroll
      for (int off = 8; off > 0; off >>= 1) {
        s1 += __shfl_xor(s1, off);
        s2 += __shfl_xor(s2, off);
      }
      if ((l & 15) == 0) { red1[row * 4 + w] = s1; red2[row * 4 + w] = s2; }
    }
  }
  __syncthreads();

#pragma unroll
  for (int m = 0; m < 4; ++m) {
#pragma unroll
    for (int j = 0; j < 4; ++j) {
      int row = m * 16 + (l >> 4) * 4 + j;
      int gr = r0 + row;
      float t1 = red1[row * 4 + 0] + red1[row * 4 + 1] +
                 red1[row * 4 + 2] + red1[row * 4 + 3];
      float t2 = red2[row * 4 + 0] + red2[row * 4 + 1] +
                 red2[row * 4 + 2] + red2[row * 4 + 3];
      float mu = t1 * (1.f / 256.f);
      float var = t2 * (1.f / 256.f) - mu * mu;
      float rs = rsqrtf(var + 1e-6f);
#pragma unroll
      for (int n = 0; n < 4; ++n) {
        int col = w * 64 + n * 16 + (l & 15);
        out[(size_t)gr * 256 + col] = (acc[m][n][j] - mu) * rs + q[m][n][j];
      }
    }
  }
}

// ---------------------------------------------------------------------------
// K2a: per-chunk local scan -> carry per chain; rst_any per (chunk,b).
// ---------------------------------------------------------------------------
__global__ __launch_bounds__(64) void k_scan_a(
    const __hip_bfloat16* __restrict__ proj, const int* __restrict__ startw,
    const float* __restrict__ ffm_a, const float* __restrict__ ffm_b,
    float2* __restrict__ carry, int* __restrict__ rstflag) {
  const int c  = blockIdx.x >> 9;        // 0..14
  const int bb = (blockIdx.x >> 4) & 31;
  const int tg = blockIdx.x & 15;
  const int tid = threadIdx.x;
  const int tl = tid >> 4, cx = tid & 15;
  const int trace = tg * 4 + tl;
  const int t0 = c * CHL;
  __shared__ float gs[CHL * 4];
  __shared__ int ss[CHL];
  for (int t = tid; t < CHL; t += 64) {
    size_t base = ((size_t)(t0 + t) * B_DIM + bb) * NP + tg * 4;
    ushortx4 pg4 = *reinterpret_cast<const ushortx4*>(proj + base);
    ushortx4 pp4 = *reinterpret_cast<const ushortx4*>(proj + base + 64);
    float4 o;
    o.x = bf2f(pp4[0]) * bf2f(pg4[0]);
    o.y = bf2f(pp4[1]) * bf2f(pg4[1]);
    o.z = bf2f(pp4[2]) * bf2f(pg4[2]);
    o.w = bf2f(pp4[3]) * bf2f(pg4[3]);
    *reinterpret_cast<float4*>(&gs[t * 4]) = o;
    ss[t] = startw[(t0 + t) * B_DIM + bb];
  }
  __syncthreads();

  int any = __any(ss[tid] != 0);
  if (tid == 0 && tg == 0) rstflag[c * B_DIM + bb] = any;

  float decay = expf(-fabsf(ffm_a[trace]));
  float th = ffm_b[cx];
  float cr = decay * cosf(th);
  float ci = decay * sinf(th);
  float sr = 0.f, si = 0.f;
  for (int t = 0; t < CHL; ++t) {
    float g = gs[t * 4 + tl];
    int rst = ss[t];
    float nr = fmaf(sr, cr, fmaf(-si, ci, g));
    float ni = fmaf(sr, ci, si * cr);
    sr = rst ? g : nr;
    si = rst ? 0.f : ni;
  }
  carry[((size_t)(c * B_DIM + bb) * TRACE + trace) * CTX + cx] =
      make_float2(sr, si);
}

// ---------------------------------------------------------------------------
// K2c v2: coalesced-store scan. One block per (b, chunk): 512 blocks x 256.
// thread = (trace = tid>>2, cq = tid&3) owns 4 chains (cx = cq*4..cq*4+3);
// per t packs 4 (re,im) dwords -> ONE uint4 store; wave covers 1KB contig.
// ---------------------------------------------------------------------------
__global__ __launch_bounds__(256) void k_scan_c(
    const __hip_bfloat16* __restrict__ proj, const int* __restrict__ startw,
    const float* __restrict__ state_re, const float* __restrict__ state_im,
    const float* __restrict__ ffm_a, const float* __restrict__ ffm_b,
    const float2* __restrict__ carry, const int* __restrict__ rstflag,
    __hip_bfloat16* __restrict__ zin, float* __restrict__ fstate) {
  const int c  = blockIdx.x >> 5;        // 0..15
  const int bb = blockIdx.x & 31;
  const int tid = threadIdx.x;
  const int trace = tid >> 2;            // 0..63
  const int cq = tid & 3;                // ctx quad
  const int t0 = c * CHL;
  __shared__ float gs[CHL * 64];         // [t][trace], 16KB
  __shared__ int ss[CHL];

  // stage gated: i over 64 t x 16 trace-quads
  for (int i = tid; i < CHL * 16; i += 256) {
    int t = i >> 4, trq = i & 15;
    size_t base = ((size_t)(t0 + t) * B_DIM + bb) * NP + trq * 4;
    ushortx4 pg4 = *reinterpret_cast<const ushortx4*>(proj + base);
    ushortx4 pp4 = *reinterpret_cast<const ushortx4*>(proj + base + 64);
    float4 o;
    o.x = bf2f(pp4[0]) * bf2f(pg4[0]);
    o.y = bf2f(pp4[1]) * bf2f(pg4[1]);
    o.z = bf2f(pp4[2]) * bf2f(pg4[2]);
    o.w = bf2f(pp4[3]) * bf2f(pg4[3]);
    *reinterpret_cast<float4*>(&gs[t * 64 + trq * 4]) = o;
  }
  for (int t = tid; t < CHL; t += 256) ss[t] = startw[(t0 + t) * B_DIM + bb];
  __syncthreads();

  float decay = expf(-fabsf(ffm_a[trace]));
  float cr[4], ci[4], sr[4], si[4];
#pragma unroll
  for (int q = 0; q < 4; ++q) {
    int cx = cq * 4 + q;
    float th = ffm_b[cx];
    cr[q] = decay * cosf(th);
    ci[q] = decay * sinf(th);
    // e^{ab*CHL} by 6 squarings
    float pr = cr[q], pi = ci[q];
#pragma unroll
    for (int s = 0; s < 6; ++s) {
      float nr = pr * pr - pi * pi;
      float ni = 2.f * pr * pi;
      pr = nr; pi = ni;
    }
    int chain = (bb * TRACE + trace) * CTX + cx;
    float asr = state_re[chain];
    float asi = state_im[chain];
    for (int j = 0; j < c; ++j) {
      float2 cj = carry[((size_t)(j * B_DIM + bb) * TRACE + trace) * CTX + cx];
      if (rstflag[j * B_DIM + bb]) {
        asr = cj.x; asi = cj.y;
      } else {
        float nsr = fmaf(pr, asr, fmaf(-pi, asi, cj.x));
        float nsi = fmaf(pr, asi, fmaf(pi, asr, cj.y));
        asr = nsr; asi = nsi;
      }
    }
    sr[q] = asr; si[q] = asi;
  }

  const size_t zbase = (size_t)trace * 32 + cq * 8;   // bf16 units
  for (int t = 0; t < CHL; ++t) {
    float g = gs[t * 64 + trace];
    int rst = ss[t];
    unsigned int u[4];
#pragma unroll
    for (int q = 0; q < 4; ++q) {
      float nr = fmaf(sr[q], cr[q], fmaf(-si[q], ci[q], g));
      float ni = fmaf(sr[q], ci[q], si[q] * cr[q]);
      sr[q] = rst ? g : nr;
      si[q] = rst ? 0.f : ni;
      u[q] = (unsigned int)__bfloat16_as_ushort(__float2bfloat16(sr[q])) |
             ((unsigned int)__bfloat16_as_ushort(__float2bfloat16(si[q])) << 16);
    }
    *reinterpret_cast<uint4*>(
        zin + ((size_t)(t0 + t) * B_DIM + bb) * KZ + zbase) =
        *reinterpret_cast<uint4*>(u);
  }
  if (c == NCH - 1) {
    float* fp = fstate + (bb * TRACE + trace) * CTX + cq * 4;
#pragma unroll
    for (int q = 0; q < 4; ++q) fp[q] = sr[q];
  }
}

extern "C" void kernel_launch(void* const* d_in, const int* in_sizes, int n_in,
                              void* d_out, int out_size, void* d_ws, size_t ws_size,
                              hipStream_t stream) {
  const float* x         = (const float*)d_in[0];
  const unsigned char* start_raw = (const unsigned char*)d_in[1];
  const float* state_re  = (const float*)d_in[2];
  const float* state_im  = (const float*)d_in[3];
  const float* w_gate_in = (const float*)d_in[4];
  const float* b_gate_in = (const float*)d_in[5];
  const float* w_pre     = (const float*)d_in[6];
  const float* b_pre     = (const float*)d_in[7];
  const float* w_z       = (const float*)d_in[8];
  const float* b_z       = (const float*)d_in[9];
  const float* w_gate_out= (const float*)d_in[10];
  const float* b_gate_out= (const float*)d_in[11];
  const float* w_skip    = (const float*)d_in[12];
  const float* b_skip    = (const float*)d_in[13];
  const float* ffm_a     = (const float*)d_in[14];
  const float* ffm_b     = (const float*)d_in[15];

  // workspace layout
  char* ws = (char*)d_ws;
  int* startw   = (int*)(ws + 4096);                          // [4KB, 132KB)
  int* rstflag  = (int*)(ws + (132 << 10));                   // [132KB, 134KB)
  float* bcat   = (float*)(ws + (160 << 10));                 // [160KB, 163KB)
  __hip_bfloat16* wcat =
      (__hip_bfloat16*)(ws + (256 << 10));                    // [256KB, 576KB)
  __hip_bfloat16* wzt =
      (__hip_bfloat16*)(ws + ((size_t)1 << 20));              // [1MB, 2MB)
  float2* carry = (float2*)(ws + ((size_t)2 << 20));          // [2MB, 6MB)
  __hip_bfloat16* proj =
      (__hip_bfloat16*)(ws + ((size_t)6 << 20));              // [6MB, 46MB)
  __hip_bfloat16* xb =
      (__hip_bfloat16*)(ws + ((size_t)46 << 20));             // [46MB, 62MB)
  __hip_bfloat16* zin =
      (__hip_bfloat16*)(ws + ((size_t)62 << 20));             // [62MB, 190MB)

  float* fstate = (float*)d_out;                    // real(final_state), 32768
  float* out    = (float*)d_out + B_DIM * TRACE * CTX;

  k_prep_all<<<4896, 256, 0, stream>>>(
      start_raw, startw, w_z, wzt,
      w_gate_in, b_gate_in, w_pre, b_pre,
      w_gate_out, b_gate_out, w_skip, b_skip,
      wcat, bcat, x, xb);
  k_gemm_xproj<<<1280, 256, 0, stream>>>(xb, wcat, bcat, proj);
  k_scan_a<<<(NCH - 1) * B_DIM * 16, 64, 0, stream>>>(
      proj, startw, ffm_a, ffm_b, carry, rstflag);
  k_scan_c<<<NCH * B_DIM, 256, 0, stream>>>(
      proj, startw, state_re, state_im, ffm_a, ffm_b, carry, rstflag,
      zin, fstate);
  k_zgemm_ln<<<TB / 64, 256, 0, stream>>>(zin, wzt, b_z, proj, out);
}

// Round 21
// 142.805 us; speedup vs baseline: 1.5523x; 1.0202x over previous
//
#include <hip/hip_runtime.h>
#include <hip/hip_bf16.h>

#define T_DIM 1024
#define B_DIM 32
#define D_DIM 256
#define TRACE 64
#define CTX 16
#define OUT_DIM 256
#define TB (T_DIM * B_DIM)          // 32768 rows
#define KZ (2 * TRACE * CTX)        // 2048
#define NP 640                      // concat proj width
#define NCH 16                      // scan chunks
#define CHL 64                      // chunk length

typedef short short8 __attribute__((ext_vector_type(8)));
typedef float floatx4 __attribute__((ext_vector_type(4)));
typedef unsigned short ushortx4 __attribute__((ext_vector_type(4)));

__device__ __forceinline__ float bf2f(unsigned short u) {
  return __uint_as_float((unsigned int)u << 16);
}
__device__ __forceinline__ float sigm(float v) {
  return 1.f / (1.f + expf(-v));
}
// async global->LDS, 16B per lane; LDS dest = wave-uniform base + lane*16
__device__ __forceinline__ void gload_lds16(const void* g, void* l) {
  __builtin_amdgcn_global_load_lds(
      (const __attribute__((address_space(1))) void*)g,
      (__attribute__((address_space(3))) void*)l, 16, 0, 0);
}

// ---------------------------------------------------------------------------
// K0: merged prep.
//  blocks [0,4096): xb = bf16(x)
//  blocks [4096,4128): start unpack (vectorized detect, 4 elems/thread)
//  blocks [4128,4256): wzt transpose
//  blocks [4256,4896): wcat/bcat
// ---------------------------------------------------------------------------
__global__ __launch_bounds__(256) void k_prep_all(
    const unsigned char* __restrict__ s, int* __restrict__ startw,
    const float* __restrict__ wz, __hip_bfloat16* __restrict__ wzt,
    const float* __restrict__ wgi, const float* __restrict__ bgi,
    const float* __restrict__ wpr, const float* __restrict__ bpr,
    const float* __restrict__ wgo, const float* __restrict__ bgo,
    const float* __restrict__ wsk, const float* __restrict__ bsk,
    __hip_bfloat16* __restrict__ wcat, float* __restrict__ bcat,
    const float* __restrict__ x, __hip_bfloat16* __restrict__ xb) {
  const int bid = blockIdx.x;
  const int tid = threadIdx.x;
  if (bid < 4096) {
    size_t i = ((size_t)bid * 256 + tid) * 8;
    float4 a = *reinterpret_cast<const float4*>(x + i);
    float4 b = *reinterpret_cast<const float4*>(x + i + 4);
    unsigned short u[8];
    u[0] = __bfloat16_as_ushort(__float2bfloat16(a.x));
    u[1] = __bfloat16_as_ushort(__float2bfloat16(a.y));
    u[2] = __bfloat16_as_ushort(__float2bfloat16(a.z));
    u[3] = __bfloat16_as_ushort(__float2bfloat16(a.w));
    u[4] = __bfloat16_as_ushort(__float2bfloat16(b.x));
    u[5] = __bfloat16_as_ushort(__float2bfloat16(b.y));
    u[6] = __bfloat16_as_ushort(__float2bfloat16(b.z));
    u[7] = __bfloat16_as_ushort(__float2bfloat16(b.w));
    *reinterpret_cast<uint4*>(xb + i) = *reinterpret_cast<uint4*>(u);
    return;
  }
  if (bid < 4128) {
    unsigned o1 = 0, o3 = 0, o4 = 0;
    for (int i = tid; i < 2048; i += 256) {
      uint4 wv = reinterpret_cast<const uint4*>(s)[i];
      unsigned allw = wv.x | wv.y | wv.z | wv.w;
      o1 |= allw & 0x0000FF00u;
      o3 |= allw & 0xFF000000u;
      o4 |= (wv.y | wv.w) & 0x000000FFu;
    }
    __shared__ unsigned s1, s3, s4;
    if (tid == 0) { s1 = 0; s3 = 0; s4 = 0; }
    __syncthreads();
    if (o1) atomicOr(&s1, 1u);
    if (o3) atomicOr(&s3, 1u);
    if (o4) atomicOr(&s4, 1u);
    __syncthreads();
    int f = s1 ? 1 : (s3 ? 2 : (s4 ? 0 : 3));
    int base = (bid - 4096) * 1024 + tid * 4;
    int4 v;
    if (f == 1) {
      uchar4 b4 = reinterpret_cast<const uchar4*>(s)[base >> 2];
      v = make_int4(b4.x != 0, b4.y != 0, b4.z != 0, b4.w != 0);
    } else if (f == 2) {
      float4 fv = reinterpret_cast<const float4*>(s)[base >> 2];
      v = make_int4(fv.x != 0.f, fv.y != 0.f, fv.z != 0.f, fv.w != 0.f);
    } else if (f == 3) {
      const long long* p = reinterpret_cast<const long long*>(s);
      v = make_int4(p[base] != 0, p[base + 1] != 0,
                    p[base + 2] != 0, p[base + 3] != 0);
    } else {
      int4 iv = reinterpret_cast<const int4*>(s)[base >> 2];
      v = make_int4(iv.x != 0, iv.y != 0, iv.z != 0, iv.w != 0);
    }
    reinterpret_cast<int4*>(startw)[base >> 2] = v;
    return;
  }
  if (bid < 4256) {
    const int t = bid - 4128;
    const int tk = t & 31;
    const int tn = t >> 5;
    const int k0 = tk * 64, n0 = tn * 64;
    __shared__ float sm[64][65];
    for (int i = tid; i < 4096; i += 256) {
      int r = i >> 6, c = i & 63;
      sm[r][c] = wz[(size_t)(k0 + r) * 256 + n0 + c];
    }
    __syncthreads();
    for (int i = tid; i < 4096; i += 256) {
      int r = i >> 6, c = i & 63;
      int src = (c & 0x20) | ((c & 1) << 4) | ((c >> 1) & 15);
      wzt[(size_t)(n0 + r) * 2048 + k0 + c] = __float2bfloat16(sm[src][r]);
    }
    return;
  }
  const int n = bid - 4256, k = tid;
  float v, bv;
  if (n < 64)        { v = wgi[k * 64 + n];          bv = bgi[n]; }
  else if (n < 128)  { v = wpr[k * 64 + (n - 64)];   bv = bpr[n - 64]; }
  else if (n < 384)  { v = wgo[k * 256 + (n - 128)]; bv = bgo[n - 128]; }
  else               { v = wsk[k * 256 + (n - 384)]; bv = bsk[n - 384]; }
  wcat[(size_t)n * 256 + k] = __float2bfloat16(v);
  if (k == 0) bcat[n] = bv;
}

// ---------------------------------------------------------------------------
// Proj GEMM (R15-proven multi-stage): proj = bf16( xb @ wcat^T + bcat ).
// ---------------------------------------------------------------------------
__global__ __launch_bounds__(256) void k_gemm_xproj(
    const __hip_bfloat16* __restrict__ A, const __hip_bfloat16* __restrict__ Bm,
    const float* __restrict__ bias, __hip_bfloat16* __restrict__ C) {
  int wg = (blockIdx.x & 7) * 160 + (blockIdx.x >> 3);
  const int n0 = (wg % 5) * 128;
  const int r0 = (wg / 5) * 128;
  const int tid = threadIdx.x;
  const int l = tid & 63;
  const int wid = tid >> 6;
  const int wr = wid >> 1;
  const int wc = wid & 1;

  __shared__ __align__(16) char ldsA[16384];
  __shared__ __align__(16) char ldsB[16384];

  floatx4 acc[4][4];
#pragma unroll
  for (int m = 0; m < 4; ++m)
#pragma unroll
    for (int n = 0; n < 4; ++n) acc[m][n] = (floatx4)0.f;

  int aoff[4][2], boff[4][2];
#pragma unroll
  for (int m = 0; m < 4; ++m) {
    int row = wr * 64 + m * 16 + (l & 15);
#pragma unroll
    for (int ks = 0; ks < 2; ++ks) {
      int byte = row * 128 + ks * 64 + (l >> 4) * 16;
      aoff[m][ks] = byte ^ ((row & 7) << 4);
    }
    int col = wc * 64 + m * 16 + (l & 15);
#pragma unroll
    for (int ks = 0; ks < 2; ++ks) {
      int byte = col * 128 + ks * 64 + (l >> 4) * 16;
      boff[m][ks] = byte ^ ((col & 7) << 4);
    }
  }

  for (int kt = 0; kt < 256; kt += 64) {
#pragma unroll
    for (int i = 0; i < 4; ++i) {
      int c = tid + i * 256;
      int row = c >> 3;
      int kgs = (c & 7) ^ (row & 7);
      gload_lds16(A + (size_t)(r0 + row) * 256 + kt + kgs * 8,
                  ldsA + i * 4096 + wid * 1024);
      gload_lds16(Bm + (size_t)(n0 + row) * 256 + kt + kgs * 8,
                  ldsB + i * 4096 + wid * 1024);
    }
    __syncthreads();
#pragma unroll
    for (int ks = 0; ks < 2; ++ks) {
      short8 a[4], b[4];
#pragma unroll
      for (int m = 0; m < 4; ++m)
        a[m] = *reinterpret_cast<const short8*>(ldsA + aoff[m][ks]);
#pragma unroll
      for (int n = 0; n < 4; ++n)
        b[n] = *reinterpret_cast<const short8*>(ldsB + boff[n][ks]);
#pragma unroll
      for (int m = 0; m < 4; ++m)
#pragma unroll
        for (int n = 0; n < 4; ++n)
          acc[m][n] = __builtin_amdgcn_mfma_f32_16x16x32_bf16(
              a[m], b[n], acc[m][n], 0, 0, 0);
    }
    __syncthreads();
  }

#pragma unroll
  for (int m = 0; m < 4; ++m) {
#pragma unroll
    for (int n = 0; n < 4; ++n) {
      int gc = n0 + wc * 64 + n * 16 + (l & 15);
      float bzv = bias[gc];
      bool dosig = (gc < 64) || (gc >= 128 && gc < 384);
#pragma unroll
      for (int j = 0; j < 4; ++j) {
        int gr = r0 + wr * 64 + m * 16 + (l >> 4) * 4 + j;
        float v = acc[m][n][j] + bzv;
        if (dosig) v = sigm(v);
        C[(size_t)gr * NP + gc] = __float2bfloat16(v);
      }
    }
  }
}

// ---------------------------------------------------------------------------
// Fused z-GEMM + LayerNorm, v8: 128M x 256N tile, 512 threads (8 waves,
// 2M x 4N, each wave 64x64). Grid 256 -> wzt L2 traffic halves vs v5.
// LDS 96KB dbuf: A0 [0,16K) A1 [16K,32K) B0 [32K,64K) B1 [64K,96K).
// Occupancy unchanged: 8 waves/CU (1 block).
// ---------------------------------------------------------------------------
__global__ __launch_bounds__(512, 1) void k_zgemm_ln(
    const __hip_bfloat16* __restrict__ zin, const __hip_bfloat16* __restrict__ wzt,
    const float* __restrict__ bz, const __hip_bfloat16* __restrict__ proj,
    float* __restrict__ out) {
  const int r0 = blockIdx.x * 128;
  const int tid = threadIdx.x;
  const int l = tid & 63;
  const int w = tid >> 6;            // wave 0..7
  const int wm = w >> 2;             // M half 0..1
  const int wn = w & 3;              // N slice 0..3

  __shared__ __align__(16) char lds[98304];
  float* red1 = (float*)lds;                   // alias A0: 128*4 floats
  float* red2 = (float*)(lds + 2048);

  floatx4 acc[4][4];
#pragma unroll
  for (int m = 0; m < 4; ++m)
#pragma unroll
    for (int n = 0; n < 4; ++n) acc[m][n] = (floatx4)0.f;

  int aoff[4][2], boff[4][2];
#pragma unroll
  for (int m = 0; m < 4; ++m) {
    int row = wm * 64 + m * 16 + (l & 15);     // 0..127
#pragma unroll
    for (int ks = 0; ks < 2; ++ks) {
      int byte = row * 128 + ks * 64 + (l >> 4) * 16;
      aoff[m][ks] = byte ^ ((row & 7) << 4);
    }
  }
#pragma unroll
  for (int n = 0; n < 4; ++n) {
    int col = wn * 64 + n * 16 + (l & 15);     // 0..255
#pragma unroll
    for (int ks = 0; ks < 2; ++ks) {
      int byte = col * 128 + ks * 64 + (l >> 4) * 16;
      boff[n][ks] = byte ^ ((col & 7) << 4);
    }
  }

  auto STAGE = [&](int kt, int sel) {
    char* pA = lds + (sel ? 16384 : 0);
    char* pB = lds + 32768 + (sel ? 32768 : 0);
    // A: 128 rows x 8 chunks = 1024 (2/thread)
#pragma unroll
    for (int i = 0; i < 2; ++i) {
      int c = tid + i * 512;
      int row = c >> 3;
      int kgs = (c & 7) ^ (row & 7);
      gload_lds16(zin + (size_t)(r0 + row) * KZ + kt + kgs * 8,
                  pA + (w * 64 + i * 512) * 16);
    }
    // B: 256 rows x 8 chunks = 2048 (4/thread)
#pragma unroll
    for (int i = 0; i < 4; ++i) {
      int c = tid + i * 512;
      int row = c >> 3;
      int kgs = (c & 7) ^ (row & 7);
      gload_lds16(wzt + (size_t)row * KZ + kt + kgs * 8,
                  pB + (w * 64 + i * 512) * 16);
    }
  };
  auto COMPUTE = [&](int sel) {
    const char* pA = lds + (sel ? 16384 : 0);
    const char* pB = lds + 32768 + (sel ? 32768 : 0);
#pragma unroll
    for (int ks = 0; ks < 2; ++ks) {
      short8 a[4], b[4];
#pragma unroll
      for (int m = 0; m < 4; ++m)
        a[m] = *reinterpret_cast<const short8*>(pA + aoff[m][ks]);
#pragma unroll
      for (int n = 0; n < 4; ++n)
        b[n] = *reinterpret_cast<const short8*>(pB + boff[n][ks]);
#pragma unroll
      for (int m = 0; m < 4; ++m)
#pragma unroll
        for (int n = 0; n < 4; ++n)
          acc[m][n] = __builtin_amdgcn_mfma_f32_16x16x32_bf16(
              a[m], b[n], acc[m][n], 0, 0, 0);
    }
  };

  STAGE(0, 0);
  asm volatile("s_waitcnt vmcnt(0)" ::: "memory");
  __builtin_amdgcn_s_barrier();
  for (int t = 0; t < 31; ++t) {
    STAGE((t + 1) * 64, (t + 1) & 1);
    COMPUTE(t & 1);
    asm volatile("s_waitcnt vmcnt(0)" ::: "memory");
    __builtin_amdgcn_s_barrier();
  }
  COMPUTE(1);  // tile 31 from buf1 — A0 dead, red aliases it

  float bzv[4];
#pragma unroll
  for (int n = 0; n < 4; ++n) bzv[n] = bz[wn * 64 + n * 16 + (l & 15)];

  // phase 1: y in-place into acc, q = ps*(1-go), wave-local partial sums
  float q[4][4][4];
#pragma unroll
  for (int m = 0; m < 4; ++m) {
#pragma unroll
    for (int j = 0; j < 4; ++j) {
      int row = wm * 64 + m * 16 + (l >> 4) * 4 + j;   // 0..127
      const __hip_bfloat16* prow = proj + (size_t)(r0 + row) * NP;
      float s1 = 0.f, s2 = 0.f;
#pragma unroll
      for (int n = 0; n < 4; ++n) {
        int col = wn * 64 + n * 16 + (l & 15);
        float go = __bfloat162float(prow[128 + col]);   // sigm precomputed
        float ps = __bfloat162float(prow[384 + col]);
        float y = (acc[m][n][j] + bzv[n]) * go;
        acc[m][n][j] = y;
        q[m][n][j] = ps * (1.f - go);
        s1 += y;
        s2 += y * y;
      }
#pragma unroll
      for (int off = 8; off > 0; off >>= 1) {
        s1 += __shfl_xor(s1, off);
        s2 += __shfl_xor(s2, off);
      }
      if ((l & 15) == 0) { red1[row * 4 + wn] = s1; red2[row * 4 + wn] = s2; }
    }
  }
  __syncthreads();

  // phase 2: combine cross-wave (4 n-slices) sums, normalize, write
#pragma unroll
  for (int m = 0; m < 4; ++m) {
#pragma unroll
    for (int j = 0; j < 4; ++j) {
      int row = wm * 64 + m * 16 + (l >> 4) * 4 + j;
      int gr = r0 + row;
      float t1 = red1[row * 4 + 0] + red1[row * 4 + 1] +
                 red1[row * 4 + 2] + red1[row * 4 + 3];
      float t2 = red2[row * 4 + 0] + red2[row * 4 + 1] +
                 red2[row * 4 + 2] + red2[row * 4 + 3];
      float mu = t1 * (1.f / 256.f);
      float var = t2 * (1.f / 256.f) - mu * mu;
      float rs = rsqrtf(var + 1e-6f);
#pragma unroll
      for (int n = 0; n < 4; ++n) {
        int col = wn * 64 + n * 16 + (l & 15);
        out[(size_t)gr * 256 + col] = (acc[m][n][j] - mu) * rs + q[m][n][j];
      }
    }
  }
}

// ---------------------------------------------------------------------------
// K2a: per-chunk local scan -> carry per chain; rst_any per (chunk,b).
// ---------------------------------------------------------------------------
__global__ __launch_bounds__(64) void k_scan_a(
    const __hip_bfloat16* __restrict__ proj, const int* __restrict__ startw,
    const float* __restrict__ ffm_a, const float* __restrict__ ffm_b,
    float2* __restrict__ carry, int* __restrict__ rstflag) {
  const int c  = blockIdx.x >> 9;        // 0..14
  const int bb = (blockIdx.x >> 4) & 31;
  const int tg = blockIdx.x & 15;
  const int tid = threadIdx.x;
  const int tl = tid >> 4, cx = tid & 15;
  const int trace = tg * 4 + tl;
  const int t0 = c * CHL;
  __shared__ float gs[CHL * 4];
  __shared__ int ss[CHL];
  for (int t = tid; t < CHL; t += 64) {
    size_t base = ((size_t)(t0 + t) * B_DIM + bb) * NP + tg * 4;
    ushortx4 pg4 = *reinterpret_cast<const ushortx4*>(proj + base);
    ushortx4 pp4 = *reinterpret_cast<const ushortx4*>(proj + base + 64);
    float4 o;
    o.x = bf2f(pp4[0]) * bf2f(pg4[0]);
    o.y = bf2f(pp4[1]) * bf2f(pg4[1]);
    o.z = bf2f(pp4[2]) * bf2f(pg4[2]);
    o.w = bf2f(pp4[3]) * bf2f(pg4[3]);
    *reinterpret_cast<float4*>(&gs[t * 4]) = o;
    ss[t] = startw[(t0 + t) * B_DIM + bb];
  }
  __syncthreads();

  int any = __any(ss[tid] != 0);
  if (tid == 0 && tg == 0) rstflag[c * B_DIM + bb] = any;

  float decay = expf(-fabsf(ffm_a[trace]));
  float th = ffm_b[cx];
  float cr = decay * cosf(th);
  float ci = decay * sinf(th);
  float sr = 0.f, si = 0.f;
  for (int t = 0; t < CHL; ++t) {
    float g = gs[t * 4 + tl];
    int rst = ss[t];
    float nr = fmaf(sr, cr, fmaf(-si, ci, g));
    float ni = fmaf(sr, ci, si * cr);
    sr = rst ? g : nr;
    si = rst ? 0.f : ni;
  }
  carry[((size_t)(c * B_DIM + bb) * TRACE + trace) * CTX + cx] =
      make_float2(sr, si);
}

// ---------------------------------------------------------------------------
// K2c v2: coalesced-store scan. One block per (b, chunk): 512 blocks x 256.
// ---------------------------------------------------------------------------
__global__ __launch_bounds__(256) void k_scan_c(
    const __hip_bfloat16* __restrict__ proj, const int* __restrict__ startw,
    const float* __restrict__ state_re, const float* __restrict__ state_im,
    const float* __restrict__ ffm_a, const float* __restrict__ ffm_b,
    const float2* __restrict__ carry, const int* __restrict__ rstflag,
    __hip_bfloat16* __restrict__ zin, float* __restrict__ fstate) {
  const int c  = blockIdx.x >> 5;        // 0..15
  const int bb = blockIdx.x & 31;
  const int tid = threadIdx.x;
  const int trace = tid >> 2;            // 0..63
  const int cq = tid & 3;                // ctx quad
  const int t0 = c * CHL;
  __shared__ float gs[CHL * 64];         // [t][trace], 16KB
  __shared__ int ss[CHL];

  for (int i = tid; i < CHL * 16; i += 256) {
    int t = i >> 4, trq = i & 15;
    size_t base = ((size_t)(t0 + t) * B_DIM + bb) * NP + trq * 4;
    ushortx4 pg4 = *reinterpret_cast<const ushortx4*>(proj + base);
    ushortx4 pp4 = *reinterpret_cast<const ushortx4*>(proj + base + 64);
    float4 o;
    o.x = bf2f(pp4[0]) * bf2f(pg4[0]);
    o.y = bf2f(pp4[1]) * bf2f(pg4[1]);
    o.z = bf2f(pp4[2]) * bf2f(pg4[2]);
    o.w = bf2f(pp4[3]) * bf2f(pg4[3]);
    *reinterpret_cast<float4*>(&gs[t * 64 + trq * 4]) = o;
  }
  for (int t = tid; t < CHL; t += 256) ss[t] = startw[(t0 + t) * B_DIM + bb];
  __syncthreads();

  float decay = expf(-fabsf(ffm_a[trace]));
  float cr[4], ci[4], sr[4], si[4];
#pragma unroll
  for (int q = 0; q < 4; ++q) {
    int cx = cq * 4 + q;
    float th = ffm_b[cx];
    cr[q] = decay * cosf(th);
    ci[q] = decay * sinf(th);
    float pr = cr[q], pi = ci[q];
#pragma unroll
    for (int s = 0; s < 6; ++s) {
      float nr = pr * pr - pi * pi;
      float ni = 2.f * pr * pi;
      pr = nr; pi = ni;
    }
    int chain = (bb * TRACE + trace) * CTX + cx;
    float asr = state_re[chain];
    float asi = state_im[chain];
    for (int j = 0; j < c; ++j) {
      float2 cj = carry[((size_t)(j * B_DIM + bb) * TRACE + trace) * CTX + cx];
      if (rstflag[j * B_DIM + bb]) {
        asr = cj.x; asi = cj.y;
      } else {
        float nsr = fmaf(pr, asr, fmaf(-pi, asi, cj.x));
        float nsi = fmaf(pr, asi, fmaf(pi, asr, cj.y));
        asr = nsr; asi = nsi;
      }
    }
    sr[q] = asr; si[q] = asi;
  }

  const size_t zbase = (size_t)trace * 32 + cq * 8;   // bf16 units
  for (int t = 0; t < CHL; ++t) {
    float g = gs[t * 64 + trace];
    int rst = ss[t];
    unsigned int u[4];
#pragma unroll
    for (int q = 0; q < 4; ++q) {
      float nr = fmaf(sr[q], cr[q], fmaf(-si[q], ci[q], g));
      float ni = fmaf(sr[q], ci[q], si[q] * cr[q]);
      sr[q] = rst ? g : nr;
      si[q] = rst ? 0.f : ni;
      u[q] = (unsigned int)__bfloat16_as_ushort(__float2bfloat16(sr[q])) |
             ((unsigned int)__bfloat16_as_ushort(__float2bfloat16(si[q])) << 16);
    }
    *reinterpret_cast<uint4*>(
        zin + ((size_t)(t0 + t) * B_DIM + bb) * KZ + zbase) =
        *reinterpret_cast<uint4*>(u);
  }
  if (c == NCH - 1) {
    float* fp = fstate + (bb * TRACE + trace) * CTX + cq * 4;
#pragma unroll
    for (int q = 0; q < 4; ++q) fp[q] = sr[q];
  }
}

extern "C" void kernel_launch(void* const* d_in, const int* in_sizes, int n_in,
                              void* d_out, int out_size, void* d_ws, size_t ws_size,
                              hipStream_t stream) {
  const float* x         = (const float*)d_in[0];
  const unsigned char* start_raw = (const unsigned char*)d_in[1];
  const float* state_re  = (const float*)d_in[2];
  const float* state_im  = (const float*)d_in[3];
  const float* w_gate_in = (const float*)d_in[4];
  const float* b_gate_in = (const float*)d_in[5];
  const float* w_pre     = (const float*)d_in[6];
  const float* b_pre     = (const float*)d_in[7];
  const float* w_z       = (const float*)d_in[8];
  const float* b_z       = (const float*)d_in[9];
  const float* w_gate_out= (const float*)d_in[10];
  const float* b_gate_out= (const float*)d_in[11];
  const float* w_skip    = (const float*)d_in[12];
  const float* b_skip    = (const float*)d_in[13];
  const float* ffm_a     = (const float*)d_in[14];
  const float* ffm_b     = (const float*)d_in[15];

  // workspace layout
  char* ws = (char*)d_ws;
  int* startw   = (int*)(ws + 4096);                          // [4KB, 132KB)
  int* rstflag  = (int*)(ws + (132 << 10));                   // [132KB, 134KB)
  float* bcat   = (float*)(ws + (160 << 10));                 // [160KB, 163KB)
  __hip_bfloat16* wcat =
      (__hip_bfloat16*)(ws + (256 << 10));                    // [256KB, 576KB)
  __hip_bfloat16* wzt =
      (__hip_bfloat16*)(ws + ((size_t)1 << 20));              // [1MB, 2MB)
  float2* carry = (float2*)(ws + ((size_t)2 << 20));          // [2MB, 6MB)
  __hip_bfloat16* proj =
      (__hip_bfloat16*)(ws + ((size_t)6 << 20));              // [6MB, 46MB)
  __hip_bfloat16* xb =
      (__hip_bfloat16*)(ws + ((size_t)46 << 20));             // [46MB, 62MB)
  __hip_bfloat16* zin =
      (__hip_bfloat16*)(ws + ((size_t)62 << 20));             // [62MB, 190MB)

  float* fstate = (float*)d_out;                    // real(final_state), 32768
  float* out    = (float*)d_out + B_DIM * TRACE * CTX;

  k_prep_all<<<4896, 256, 0, stream>>>(
      start_raw, startw, w_z, wzt,
      w_gate_in, b_gate_in, w_pre, b_pre,
      w_gate_out, b_gate_out, w_skip, b_skip,
      wcat, bcat, x, xb);
  k_gemm_xproj<<<1280, 256, 0, stream>>>(xb, wcat, bcat, proj);
  k_scan_a<<<(NCH - 1) * B_DIM * 16, 64, 0, stream>>>(
      proj, startw, ffm_a, ffm_b, carry, rstflag);
  k_scan_c<<<NCH * B_DIM, 256, 0, stream>>>(
      proj, startw, state_re, state_im, ffm_a, ffm_b, carry, rstflag,
      zin, fstate);
  k_zgemm_ln<<<TB / 128, 512, 0, stream>>>(zin, wzt, b_z, proj, out);
}